// Round 1
// baseline (1548.201 us; speedup 1.0000x reference)
//
#include <hip/hip_runtime.h>
#include <math.h>

// Problem constants
#define B_N  4096
#define D_IN 1024
#define D_D  256
#define K_C  1024
#define L_Q  32768
#define KQ_  4096   // K * Q_MULT

// ---------------- block reduction helpers (blockDim == 256) ----------------
__device__ __forceinline__ float bsum(float v, float* sb) {
  int t = threadIdx.x;
  sb[t] = v; __syncthreads();
  #pragma unroll
  for (int s = 128; s > 0; s >>= 1) {
    if (t < s) sb[t] += sb[t + s];
    __syncthreads();
  }
  float r = sb[0]; __syncthreads();
  return r;
}

__device__ __forceinline__ float bmax(float v, float* sb) {
  int t = threadIdx.x;
  sb[t] = v; __syncthreads();
  #pragma unroll
  for (int s = 128; s > 0; s >>= 1) {
    if (t < s) sb[t] = fmaxf(sb[t], sb[t + s]);
    __syncthreads();
  }
  float r = sb[0]; __syncthreads();
  return r;
}

// ---------------- row L2-normalize kernels (row length = 256) ----------------
__global__ __launch_bounds__(256) void k_rownorm(const float* __restrict__ src,
                                                 float* __restrict__ dst) {
  __shared__ float sb[256];
  int row = blockIdx.x, tid = threadIdx.x;
  float v = src[(size_t)row * 256 + tid];
  float ss = bsum(v * v, sb);
  dst[(size_t)row * 256 + tid] = v * rsqrtf(fmaxf(ss, 1e-12f));
}

// dst = l2norm(2*a + b)
__global__ __launch_bounds__(256) void k_rownorm_comb(const float* __restrict__ a,
                                                      const float* __restrict__ b,
                                                      float* __restrict__ dst) {
  __shared__ float sb[256];
  int row = blockIdx.x, tid = threadIdx.x;
  size_t i = (size_t)row * 256 + tid;
  float v = 2.0f * a[i] + b[i];
  float ss = bsum(v * v, sb);
  dst[i] = v * rsqrtf(fmaxf(ss, 1e-12f));
}

// dst = l2norm(src / (norm[row] + EPS))
__global__ __launch_bounds__(256) void k_rownorm_div(const float* __restrict__ src,
                                                     const float* __restrict__ norm,
                                                     float* __restrict__ dst) {
  __shared__ float sb[256];
  int row = blockIdx.x, tid = threadIdx.x;
  size_t i = (size_t)row * 256 + tid;
  float v = src[i] / (norm[row] + 1e-8f);
  float ss = bsum(v * v, sb);
  dst[i] = v * rsqrtf(fmaxf(ss, 1e-12f));
}

// out[row] = dot(a[row,:], b[row,:]) over 256
__global__ __launch_bounds__(256) void k_dotrows(const float* __restrict__ a,
                                                 const float* __restrict__ b,
                                                 float* __restrict__ out) {
  __shared__ float sb[256];
  int row = blockIdx.x, tid = threadIdx.x;
  size_t i = (size_t)row * 256 + tid;
  float s = bsum(a[i] * b[i], sb);
  if (tid == 0) out[row] = s;
}

// ---------------- GEMM NN: C[M,N] = A[M,K] @ B[K,N], 64x64x16 tiles ----------------
__global__ __launch_bounds__(256) void k_gemm_nn(const float* __restrict__ A,
                                                 const float* __restrict__ Bm,
                                                 float* __restrict__ C,
                                                 int M, int N, int K) {
  __shared__ float As[16][68];
  __shared__ float Bs[16][68];
  const int tid = threadIdx.x;
  const int tx = tid & 15, ty = tid >> 4;
  const int bx = blockIdx.x, by = blockIdx.y;
  const int ar = tid >> 2, ac4 = (tid & 3) << 2;   // A loader: 64 rows x 16 k
  const int br = tid >> 4, bc4 = (tid & 15) << 2;  // B loader: 16 k x 64 n
  float acc[4][4] = {};
  const float* Ap = A + (size_t)(by * 64 + ar) * K + ac4;
  const float* Bp = Bm + (size_t)br * N + bx * 64 + bc4;
  for (int k0 = 0; k0 < K; k0 += 16) {
    float4 av = *(const float4*)(Ap + k0);
    As[ac4 + 0][ar] = av.x; As[ac4 + 1][ar] = av.y;
    As[ac4 + 2][ar] = av.z; As[ac4 + 3][ar] = av.w;
    *(float4*)&Bs[br][bc4] = *(const float4*)(Bp + (size_t)k0 * N);
    __syncthreads();
    #pragma unroll
    for (int kk = 0; kk < 16; ++kk) {
      float4 a = *(const float4*)&As[kk][ty << 2];
      float4 b = *(const float4*)&Bs[kk][tx << 2];
      float af[4] = {a.x, a.y, a.z, a.w};
      float bf[4] = {b.x, b.y, b.z, b.w};
      #pragma unroll
      for (int i = 0; i < 4; ++i)
        #pragma unroll
        for (int j = 0; j < 4; ++j)
          acc[i][j] = fmaf(af[i], bf[j], acc[i][j]);
    }
    __syncthreads();
  }
  float* Cp = C + (size_t)(by * 64 + (ty << 2)) * N + bx * 64 + (tx << 2);
  #pragma unroll
  for (int i = 0; i < 4; ++i) {
    float4 o = make_float4(acc[i][0], acc[i][1], acc[i][2], acc[i][3]);
    *(float4*)(Cp + (size_t)i * N) = o;
  }
}

// ---------------- GEMM NT: C[M,N] = A[M,K] @ B[N,K]^T ----------------
__global__ __launch_bounds__(256) void k_gemm_nt(const float* __restrict__ A,
                                                 const float* __restrict__ Bm,
                                                 float* __restrict__ C,
                                                 int M, int N, int K) {
  __shared__ float As[16][68];
  __shared__ float Bs[16][68];
  const int tid = threadIdx.x;
  const int tx = tid & 15, ty = tid >> 4;
  const int bx = blockIdx.x, by = blockIdx.y;
  const int lr = tid >> 2, lc4 = (tid & 3) << 2;   // loader: 64 rows x 16 k
  float acc[4][4] = {};
  const float* Ap = A + (size_t)(by * 64 + lr) * K + lc4;
  const float* Bp = Bm + (size_t)(bx * 64 + lr) * K + lc4;
  for (int k0 = 0; k0 < K; k0 += 16) {
    float4 av = *(const float4*)(Ap + k0);
    As[lc4 + 0][lr] = av.x; As[lc4 + 1][lr] = av.y;
    As[lc4 + 2][lr] = av.z; As[lc4 + 3][lr] = av.w;
    float4 bv = *(const float4*)(Bp + k0);
    Bs[lc4 + 0][lr] = bv.x; Bs[lc4 + 1][lr] = bv.y;
    Bs[lc4 + 2][lr] = bv.z; Bs[lc4 + 3][lr] = bv.w;
    __syncthreads();
    #pragma unroll
    for (int kk = 0; kk < 16; ++kk) {
      float4 a = *(const float4*)&As[kk][ty << 2];
      float4 b = *(const float4*)&Bs[kk][tx << 2];
      float af[4] = {a.x, a.y, a.z, a.w};
      float bf[4] = {b.x, b.y, b.z, b.w};
      #pragma unroll
      for (int i = 0; i < 4; ++i)
        #pragma unroll
        for (int j = 0; j < 4; ++j)
          acc[i][j] = fmaf(af[i], bf[j], acc[i][j]);
    }
    __syncthreads();
  }
  float* Cp = C + (size_t)(by * 64 + (ty << 2)) * N + bx * 64 + (tx << 2);
  #pragma unroll
  for (int i = 0; i < 4; ++i) {
    float4 o = make_float4(acc[i][0], acc[i][1], acc[i][2], acc[i][3]);
    *(float4*)(Cp + (size_t)i * N) = o;
  }
}

// ---------------- GEMM TN w/ split-K atomics: C[k,d] += sum_b Y[b,k]*F[b,d] ----------------
__global__ __launch_bounds__(256) void k_gemm_tn(const float* __restrict__ Y,
                                                 const float* __restrict__ F,
                                                 float* __restrict__ C,
                                                 int Kc, int Dd, int chunk) {
  __shared__ float As[16][68];  // [b][k]
  __shared__ float Bs[16][68];  // [b][d]
  const int tid = threadIdx.x;
  const int tx = tid & 15, ty = tid >> 4;
  const int bx = blockIdx.x, by = blockIdx.y, bz = blockIdx.z;
  const int lr = tid >> 4, lc4 = (tid & 15) << 2;  // loader: 16 b x 64 cols
  float acc[4][4] = {};
  const int b0 = bz * chunk;
  for (int bb = b0; bb < b0 + chunk; bb += 16) {
    *(float4*)&As[lr][lc4] = *(const float4*)(Y + (size_t)(bb + lr) * Kc + by * 64 + lc4);
    *(float4*)&Bs[lr][lc4] = *(const float4*)(F + (size_t)(bb + lr) * Dd + bx * 64 + lc4);
    __syncthreads();
    #pragma unroll
    for (int kk = 0; kk < 16; ++kk) {
      float4 a = *(const float4*)&As[kk][ty << 2];
      float4 b = *(const float4*)&Bs[kk][tx << 2];
      float af[4] = {a.x, a.y, a.z, a.w};
      float bf[4] = {b.x, b.y, b.z, b.w};
      #pragma unroll
      for (int i = 0; i < 4; ++i)
        #pragma unroll
        for (int j = 0; j < 4; ++j)
          acc[i][j] = fmaf(af[i], bf[j], acc[i][j]);
    }
    __syncthreads();
  }
  #pragma unroll
  for (int i = 0; i < 4; ++i)
    #pragma unroll
    for (int j = 0; j < 4; ++j)
      atomicAdd(&C[(size_t)(by * 64 + (ty << 2) + i) * Dd + bx * 64 + (tx << 2) + j],
                acc[i][j]);
}

// ---------------- column sums of Y [Bb, Kc] -> norm[k] (atomic partials) ----------------
__global__ __launch_bounds__(256) void k_colsum(const float* __restrict__ Y,
                                                float* __restrict__ norm,
                                                int Bb, int Kc) {
  int k = blockIdx.x * 256 + threadIdx.x;
  int chunk = Bb / gridDim.y;
  int b0 = blockIdx.y * chunk;
  float s = 0.0f;
  for (int b = b0; b < b0 + chunk; ++b) s += Y[(size_t)b * Kc + k];
  atomicAdd(&norm[k], s);
}

// ---------------- gumbel softmax (in-place on logits), optional hard argmax ----------------
__global__ __launch_bounds__(256) void k_gumbel(float* __restrict__ Y,
                                                const float* __restrict__ Ua,
                                                const float* __restrict__ Ub,
                                                float* __restrict__ assign_out,
                                                int Kc) {
  __shared__ float sb[256];
  __shared__ float svals[256];
  __shared__ int sidx[256];
  int row = blockIdx.x, tid = threadIdx.x;
  float* ya = Y + (size_t)row * Kc;
  float l[4], s[4];
  float lm = -3.4e38f;
  #pragma unroll
  for (int j = 0; j < 4; ++j) {
    int k = j * 256 + tid;
    l[j] = ya[k];
    float u = Ua[(size_t)row * Kc + k];
    u = u * (1.0f - 2e-6f) + 1e-6f;
    float g = -logf(-logf(u));
    s[j] = (l[j] + g) * 2.0f;   // / GUMBEL_TEMP (0.5)
    lm = fmaxf(lm, s[j]);
  }
  float m = bmax(lm, sb);
  float e[4]; float sum = 0.0f;
  #pragma unroll
  for (int j = 0; j < 4; ++j) { e[j] = expf(s[j] - m); sum += e[j]; }
  sum = bsum(sum, sb);
  #pragma unroll
  for (int j = 0; j < 4; ++j) ya[j * 256 + tid] = e[j] / sum;

  if (Ub != nullptr) {
    float bv = -3.4e38f; int bi = 0x7fffffff;
    #pragma unroll
    for (int j = 0; j < 4; ++j) {
      int k = j * 256 + tid;
      float u = Ub[(size_t)row * Kc + k];
      u = u * (1.0f - 2e-6f) + 1e-6f;
      float g = -logf(-logf(u));
      float t = l[j] + g;
      if (t > bv || (t == bv && k < bi)) { bv = t; bi = k; }
    }
    svals[tid] = bv; sidx[tid] = bi; __syncthreads();
    for (int st = 128; st > 0; st >>= 1) {
      if (tid < st) {
        if (svals[tid + st] > svals[tid] ||
            (svals[tid + st] == svals[tid] && sidx[tid + st] < sidx[tid])) {
          svals[tid] = svals[tid + st]; sidx[tid] = sidx[tid + st];
        }
      }
      __syncthreads();
    }
    if (tid == 0) assign_out[row] = (float)sidx[0];
  }
}

// ---------------- big GEMM-NT with exp-reduce epilogue ----------------
// sumexp[row] += sum_cols exp(dot(A[row], B[col]) / TEMP); tiles 128x128x16, micro 8x8
__global__ __launch_bounds__(256) void k_lse(const float* __restrict__ A,
                                             const float* __restrict__ Bm,
                                             float* __restrict__ sumexp) {
  __shared__ float As[16][132];
  __shared__ float Bs[16][132];
  const int tid = threadIdx.x;
  const int tx = tid & 15, ty = tid >> 4;
  const int bx = blockIdx.x, by = blockIdx.y;
  const int lr = tid >> 2, lc4 = (tid & 3) << 2;  // loader: 64 rows x 16 d (x2 row groups)
  float acc[8][8] = {};
  const float* Ab = A + (size_t)(by * 128 + lr) * 256 + lc4;
  const float* Bb = Bm + (size_t)(bx * 128 + lr) * 256 + lc4;
  for (int d0 = 0; d0 < 256; d0 += 16) {
    #pragma unroll
    for (int rr = 0; rr < 128; rr += 64) {
      float4 av = *(const float4*)(Ab + (size_t)rr * 256 + d0);
      As[lc4 + 0][lr + rr] = av.x; As[lc4 + 1][lr + rr] = av.y;
      As[lc4 + 2][lr + rr] = av.z; As[lc4 + 3][lr + rr] = av.w;
      float4 bv = *(const float4*)(Bb + (size_t)rr * 256 + d0);
      Bs[lc4 + 0][lr + rr] = bv.x; Bs[lc4 + 1][lr + rr] = bv.y;
      Bs[lc4 + 2][lr + rr] = bv.z; Bs[lc4 + 3][lr + rr] = bv.w;
    }
    __syncthreads();
    #pragma unroll
    for (int kk = 0; kk < 16; ++kk) {
      float4 a0 = *(const float4*)&As[kk][ty << 2];
      float4 a1 = *(const float4*)&As[kk][64 + (ty << 2)];
      float4 b0 = *(const float4*)&Bs[kk][tx << 2];
      float4 b1 = *(const float4*)&Bs[kk][64 + (tx << 2)];
      float af[8] = {a0.x, a0.y, a0.z, a0.w, a1.x, a1.y, a1.z, a1.w};
      float bf[8] = {b0.x, b0.y, b0.z, b0.w, b1.x, b1.y, b1.z, b1.w};
      #pragma unroll
      for (int i = 0; i < 8; ++i)
        #pragma unroll
        for (int j = 0; j < 8; ++j)
          acc[i][j] = fmaf(af[i], bf[j], acc[i][j]);
    }
    __syncthreads();
  }
  const float invT = 1.0f / 0.07f;
  #pragma unroll
  for (int i = 0; i < 8; ++i) {
    float rs = 0.0f;
    #pragma unroll
    for (int j = 0; j < 8; ++j) rs += expf(acc[i][j] * invT);
    #pragma unroll
    for (int off = 1; off < 16; off <<= 1) rs += __shfl_xor(rs, off);
    if (tx == 0) {
      int row = by * 128 + ((i < 4) ? ((ty << 2) + i) : (64 + (ty << 2) + i - 4));
      atomicAdd(&sumexp[row], rs);
    }
  }
}

// ---------------- final loss ----------------
__global__ __launch_bounds__(256) void k_loss(const float* __restrict__ lpn,
                                              const float* __restrict__ sen, int nb,
                                              const float* __restrict__ lpk,
                                              const float* __restrict__ sek, int nk,
                                              float* __restrict__ out) {
  __shared__ float sb[256];
  int tid = threadIdx.x;
  const float invT = 1.0f / 0.07f;
  float s = 0.0f;
  for (int b = tid; b < nb; b += 256) {
    float lp = lpn[b] * invT;
    s += logf(expf(lp) + sen[b]) - lp;
  }
  float s1 = bsum(s, sb);
  s = 0.0f;
  for (int b = tid; b < nk; b += 256) {
    float lp = lpk[b] * invT;
    s += logf(expf(lp) + sek[b]) - lp;
  }
  float s2 = bsum(s, sb);
  if (tid == 0) out[0] = s1 / (float)nb + s2 / (float)nk;
}

// ---------------- launcher ----------------
extern "C" void kernel_launch(void* const* d_in, const int* in_sizes, int n_in,
                              void* d_out, int out_size, void* d_ws, size_t ws_size,
                              hipStream_t stream) {
  const float* x1     = (const float*)d_in[0];
  const float* x2     = (const float*)d_in[1];
  const float* W1     = (const float*)d_in[2];
  const float* W2     = (const float*)d_in[3];
  const float* c1     = (const float*)d_in[4];
  const float* c2     = (const float*)d_in[5];
  const float* qn     = (const float*)d_in[6];
  const float* qk     = (const float*)d_in[7];
  const float* u1a    = (const float*)d_in[8];
  const float* u1b    = (const float*)d_in[9];
  const float* u2a    = (const float*)d_in[10];
  // d_in[11] (u2b) only feeds the discarded _assign_2 — skipped
  const float* qnoise = (const float*)d_in[12];

  float* out_assign = (float*)d_out;              // [4096]
  float* out_feat2  = out_assign + B_N;           // agg_n_2 == feat_2 [4096,256]
  float* out_aggk2  = out_feat2 + (size_t)B_N * D_D;  // agg_k_2 [1024,256]
  float* out_loss   = out_aggk2 + (size_t)K_C * D_D;  // scalar

  float* w = (float*)d_ws;
  float* f1    = w; w += (size_t)B_N * D_D;
  float* ctx1n = w; w += (size_t)K_C * D_D;
  float* ctx2n = w; w += (size_t)K_C * D_D;
  float* qnn   = w; w += (size_t)L_Q * D_D;
  float* qkn   = w; w += (size_t)KQ_ * D_D;
  float* qcomb = w; w += (size_t)KQ_ * D_D;
  float* ybuf  = w; w += (size_t)B_N * K_C;
  float* aggk1 = w; w += (size_t)K_C * D_D;
  float* zero0 = w;
  float* aggt1 = w; w += (size_t)K_C * D_D;
  float* aggt2 = w; w += (size_t)K_C * D_D;
  float* norm1 = w; w += K_C;
  float* norm2 = w; w += K_C;
  float* sen   = w; w += B_N;
  float* sek   = w; w += K_C;
  float* lpn   = w; w += B_N;
  float* lpk   = w; w += K_C;
  size_t zbytes = (size_t)((float*)w - zero0 - B_N - K_C) * sizeof(float); // aggt1..sek
  hipMemsetAsync(zero0, 0, zbytes, stream);

  // features: feat = l2norm(x @ W)
  k_gemm_nn<<<dim3(D_D / 64, B_N / 64), 256, 0, stream>>>(x1, W1, f1, B_N, D_D, D_IN);
  k_rownorm<<<B_N, 256, 0, stream>>>(f1, f1);
  k_gemm_nn<<<dim3(D_D / 64, B_N / 64), 256, 0, stream>>>(x2, W2, out_feat2, B_N, D_D, D_IN);
  k_rownorm<<<B_N, 256, 0, stream>>>(out_feat2, out_feat2);

  // normalize contexts / queues
  k_rownorm<<<K_C, 256, 0, stream>>>(c1, ctx1n);
  k_rownorm<<<K_C, 256, 0, stream>>>(c2, ctx2n);
  k_rownorm<<<L_Q, 256, 0, stream>>>(qn, qnn);
  k_rownorm<<<KQ_, 256, 0, stream>>>(qk, qkn);
  k_rownorm_comb<<<KQ_, 256, 0, stream>>>(qkn, qnoise, qcomb);

  // view 1: logits -> gumbel softmax (+hard argmax) -> agg
  k_gemm_nt<<<dim3(K_C / 64, B_N / 64), 256, 0, stream>>>(f1, ctx1n, ybuf, B_N, K_C, D_D);
  k_gumbel<<<B_N, 256, 0, stream>>>(ybuf, u1a, u1b, out_assign, K_C);
  k_colsum<<<dim3(K_C / 256, 16), 256, 0, stream>>>(ybuf, norm1, B_N, K_C);
  k_gemm_tn<<<dim3(D_D / 64, K_C / 64, 8), 256, 0, stream>>>(ybuf, f1, aggt1, K_C, D_D, B_N / 8);
  k_rownorm_div<<<K_C, 256, 0, stream>>>(aggt1, norm1, aggk1);

  // view 2 (soft only; hard result is discarded by reference)
  k_gemm_nt<<<dim3(K_C / 64, B_N / 64), 256, 0, stream>>>(out_feat2, ctx2n, ybuf, B_N, K_C, D_D);
  k_gumbel<<<B_N, 256, 0, stream>>>(ybuf, u2a, nullptr, nullptr, K_C);
  k_colsum<<<dim3(K_C / 256, 16), 256, 0, stream>>>(ybuf, norm2, B_N, K_C);
  k_gemm_tn<<<dim3(D_D / 64, K_C / 64, 8), 256, 0, stream>>>(ybuf, out_feat2, aggt2, K_C, D_D, B_N / 8);
  k_rownorm_div<<<K_C, 256, 0, stream>>>(aggt2, norm2, out_aggk2);

  // positives
  k_dotrows<<<B_N, 256, 0, stream>>>(f1, out_feat2, lpn);
  k_dotrows<<<K_C, 256, 0, stream>>>(aggk1, out_aggk2, lpk);

  // negative-logit LSE reductions (the big one: 4096 x 32768 x 256)
  k_lse<<<dim3(L_Q / 128, B_N / 128), 256, 0, stream>>>(f1, qnn, sen);
  k_lse<<<dim3(KQ_ / 128, K_C / 128), 256, 0, stream>>>(aggk1, qcomb, sek);

  // final scalar loss
  k_loss<<<1, 256, 0, stream>>>(lpn, sen, B_N, lpk, sek, K_C, out_loss);
}

// Round 2
// 973.429 us; speedup vs baseline: 1.5905x; 1.5905x over previous
//
#include <hip/hip_runtime.h>
#include <hip/hip_bf16.h>
#include <math.h>

#define B_N  4096
#define D_IN 1024
#define D_D  256
#define K_C  1024
#define L_Q  32768
#define KQ_  4096

typedef __attribute__((ext_vector_type(8))) short short8_t;
typedef __attribute__((ext_vector_type(4))) float f32x4_t;

__device__ __forceinline__ float bsum(float v, float* sb) {
  int t = threadIdx.x;
  sb[t] = v; __syncthreads();
  #pragma unroll
  for (int s = 128; s > 0; s >>= 1) {
    if (t < s) sb[t] += sb[t + s];
    __syncthreads();
  }
  float r = sb[0]; __syncthreads();
  return r;
}

__device__ __forceinline__ float bmax(float v, float* sb) {
  int t = threadIdx.x;
  sb[t] = v; __syncthreads();
  #pragma unroll
  for (int s = 128; s > 0; s >>= 1) {
    if (t < s) sb[t] = fmaxf(sb[t], sb[t + s]);
    __syncthreads();
  }
  float r = sb[0]; __syncthreads();
  return r;
}

__global__ __launch_bounds__(256) void k_rownorm(const float* __restrict__ src,
                                                 float* __restrict__ dst) {
  __shared__ float sb[256];
  int row = blockIdx.x, tid = threadIdx.x;
  float v = src[(size_t)row * 256 + tid];
  float ss = bsum(v * v, sb);
  dst[(size_t)row * 256 + tid] = v * rsqrtf(fmaxf(ss, 1e-12f));
}

__global__ __launch_bounds__(256) void k_rownorm_bf16(const float* __restrict__ src,
                                                      __hip_bfloat16* __restrict__ dst) {
  __shared__ float sb[256];
  int row = blockIdx.x, tid = threadIdx.x;
  float v = src[(size_t)row * 256 + tid];
  float ss = bsum(v * v, sb);
  dst[(size_t)row * 256 + tid] = __float2bfloat16(v * rsqrtf(fmaxf(ss, 1e-12f)));
}

__global__ __launch_bounds__(256) void k_rownorm_dual(const float* __restrict__ src,
                                                      float* __restrict__ dstf,
                                                      __hip_bfloat16* __restrict__ dstb) {
  __shared__ float sb[256];
  int row = blockIdx.x, tid = threadIdx.x;
  float v = src[(size_t)row * 256 + tid];
  float ss = bsum(v * v, sb);
  float o = v * rsqrtf(fmaxf(ss, 1e-12f));
  dstf[(size_t)row * 256 + tid] = o;
  dstb[(size_t)row * 256 + tid] = __float2bfloat16(o);
}

__global__ __launch_bounds__(256) void k_rownorm_comb_bf16(const float* __restrict__ a,
                                                           const float* __restrict__ b,
                                                           __hip_bfloat16* __restrict__ dst) {
  __shared__ float sb[256];
  int row = blockIdx.x, tid = threadIdx.x;
  size_t i = (size_t)row * 256 + tid;
  float v = 2.0f * a[i] + b[i];
  float ss = bsum(v * v, sb);
  dst[i] = __float2bfloat16(v * rsqrtf(fmaxf(ss, 1e-12f)));
}

__global__ __launch_bounds__(256) void k_rownorm_div(const float* __restrict__ src,
                                                     const float* __restrict__ norm,
                                                     float* __restrict__ dst) {
  __shared__ float sb[256];
  int row = blockIdx.x, tid = threadIdx.x;
  size_t i = (size_t)row * 256 + tid;
  float v = src[i] / (norm[row] + 1e-8f);
  float ss = bsum(v * v, sb);
  dst[i] = v * rsqrtf(fmaxf(ss, 1e-12f));
}

__global__ __launch_bounds__(256) void k_rownorm_div_dual(const float* __restrict__ src,
                                                          const float* __restrict__ norm,
                                                          float* __restrict__ dstf,
                                                          __hip_bfloat16* __restrict__ dstb) {
  __shared__ float sb[256];
  int row = blockIdx.x, tid = threadIdx.x;
  size_t i = (size_t)row * 256 + tid;
  float v = src[i] / (norm[row] + 1e-8f);
  float ss = bsum(v * v, sb);
  float o = v * rsqrtf(fmaxf(ss, 1e-12f));
  dstf[i] = o;
  dstb[i] = __float2bfloat16(o);
}

__global__ __launch_bounds__(256) void k_dotrows(const float* __restrict__ a,
                                                 const float* __restrict__ b,
                                                 float* __restrict__ out) {
  __shared__ float sb[256];
  int row = blockIdx.x, tid = threadIdx.x;
  size_t i = (size_t)row * 256 + tid;
  float s = bsum(a[i] * b[i], sb);
  if (tid == 0) out[row] = s;
}

__global__ __launch_bounds__(256) void k_gemm_nn(const float* __restrict__ A,
                                                 const float* __restrict__ Bm,
                                                 float* __restrict__ C,
                                                 int M, int N, int K) {
  __shared__ float As[16][68];
  __shared__ float Bs[16][68];
  const int tid = threadIdx.x;
  const int tx = tid & 15, ty = tid >> 4;
  const int bx = blockIdx.x, by = blockIdx.y;
  const int ar = tid >> 2, ac4 = (tid & 3) << 2;
  const int br = tid >> 4, bc4 = (tid & 15) << 2;
  float acc[4][4] = {};
  const float* Ap = A + (size_t)(by * 64 + ar) * K + ac4;
  const float* Bp = Bm + (size_t)br * N + bx * 64 + bc4;
  for (int k0 = 0; k0 < K; k0 += 16) {
    float4 av = *(const float4*)(Ap + k0);
    As[ac4 + 0][ar] = av.x; As[ac4 + 1][ar] = av.y;
    As[ac4 + 2][ar] = av.z; As[ac4 + 3][ar] = av.w;
    *(float4*)&Bs[br][bc4] = *(const float4*)(Bp + (size_t)k0 * N);
    __syncthreads();
    #pragma unroll
    for (int kk = 0; kk < 16; ++kk) {
      float4 a = *(const float4*)&As[kk][ty << 2];
      float4 b = *(const float4*)&Bs[kk][tx << 2];
      float af[4] = {a.x, a.y, a.z, a.w};
      float bf[4] = {b.x, b.y, b.z, b.w};
      #pragma unroll
      for (int i = 0; i < 4; ++i)
        #pragma unroll
        for (int j = 0; j < 4; ++j)
          acc[i][j] = fmaf(af[i], bf[j], acc[i][j]);
    }
    __syncthreads();
  }
  float* Cp = C + (size_t)(by * 64 + (ty << 2)) * N + bx * 64 + (tx << 2);
  #pragma unroll
  for (int i = 0; i < 4; ++i) {
    float4 o = make_float4(acc[i][0], acc[i][1], acc[i][2], acc[i][3]);
    *(float4*)(Cp + (size_t)i * N) = o;
  }
}

__global__ __launch_bounds__(256) void k_gemm_nt(const float* __restrict__ A,
                                                 const float* __restrict__ Bm,
                                                 float* __restrict__ C,
                                                 int M, int N, int K) {
  __shared__ float As[16][68];
  __shared__ float Bs[16][68];
  const int tid = threadIdx.x;
  const int tx = tid & 15, ty = tid >> 4;
  const int bx = blockIdx.x, by = blockIdx.y;
  const int lr = tid >> 2, lc4 = (tid & 3) << 2;
  float acc[4][4] = {};
  const float* Ap = A + (size_t)(by * 64 + lr) * K + lc4;
  const float* Bp = Bm + (size_t)(bx * 64 + lr) * K + lc4;
  for (int k0 = 0; k0 < K; k0 += 16) {
    float4 av = *(const float4*)(Ap + k0);
    As[lc4 + 0][lr] = av.x; As[lc4 + 1][lr] = av.y;
    As[lc4 + 2][lr] = av.z; As[lc4 + 3][lr] = av.w;
    float4 bv = *(const float4*)(Bp + k0);
    Bs[lc4 + 0][lr] = bv.x; Bs[lc4 + 1][lr] = bv.y;
    Bs[lc4 + 2][lr] = bv.z; Bs[lc4 + 3][lr] = bv.w;
    __syncthreads();
    #pragma unroll
    for (int kk = 0; kk < 16; ++kk) {
      float4 a = *(const float4*)&As[kk][ty << 2];
      float4 b = *(const float4*)&Bs[kk][tx << 2];
      float af[4] = {a.x, a.y, a.z, a.w};
      float bf[4] = {b.x, b.y, b.z, b.w};
      #pragma unroll
      for (int i = 0; i < 4; ++i)
        #pragma unroll
        for (int j = 0; j < 4; ++j)
          acc[i][j] = fmaf(af[i], bf[j], acc[i][j]);
    }
    __syncthreads();
  }
  float* Cp = C + (size_t)(by * 64 + (ty << 2)) * N + bx * 64 + (tx << 2);
  #pragma unroll
  for (int i = 0; i < 4; ++i) {
    float4 o = make_float4(acc[i][0], acc[i][1], acc[i][2], acc[i][3]);
    *(float4*)(Cp + (size_t)i * N) = o;
  }
}

__global__ __launch_bounds__(256) void k_gemm_tn(const float* __restrict__ Y,
                                                 const float* __restrict__ F,
                                                 float* __restrict__ C,
                                                 int Kc, int Dd, int chunk) {
  __shared__ float As[16][68];
  __shared__ float Bs[16][68];
  const int tid = threadIdx.x;
  const int tx = tid & 15, ty = tid >> 4;
  const int bx = blockIdx.x, by = blockIdx.y, bz = blockIdx.z;
  const int lr = tid >> 4, lc4 = (tid & 15) << 2;
  float acc[4][4] = {};
  const int b0 = bz * chunk;
  for (int bb = b0; bb < b0 + chunk; bb += 16) {
    *(float4*)&As[lr][lc4] = *(const float4*)(Y + (size_t)(bb + lr) * Kc + by * 64 + lc4);
    *(float4*)&Bs[lr][lc4] = *(const float4*)(F + (size_t)(bb + lr) * Dd + bx * 64 + lc4);
    __syncthreads();
    #pragma unroll
    for (int kk = 0; kk < 16; ++kk) {
      float4 a = *(const float4*)&As[kk][ty << 2];
      float4 b = *(const float4*)&Bs[kk][tx << 2];
      float af[4] = {a.x, a.y, a.z, a.w};
      float bf[4] = {b.x, b.y, b.z, b.w};
      #pragma unroll
      for (int i = 0; i < 4; ++i)
        #pragma unroll
        for (int j = 0; j < 4; ++j)
          acc[i][j] = fmaf(af[i], bf[j], acc[i][j]);
    }
    __syncthreads();
  }
  #pragma unroll
  for (int i = 0; i < 4; ++i)
    #pragma unroll
    for (int j = 0; j < 4; ++j)
      atomicAdd(&C[(size_t)(by * 64 + (ty << 2) + i) * Dd + bx * 64 + (tx << 2) + j],
                acc[i][j]);
}

__global__ __launch_bounds__(256) void k_colsum(const float* __restrict__ Y,
                                                float* __restrict__ norm,
                                                int Bb, int Kc) {
  int k = blockIdx.x * 256 + threadIdx.x;
  int chunk = Bb / gridDim.y;
  int b0 = blockIdx.y * chunk;
  float s = 0.0f;
  for (int b = b0; b < b0 + chunk; ++b) s += Y[(size_t)b * Kc + k];
  atomicAdd(&norm[k], s);
}

__global__ __launch_bounds__(256) void k_gumbel(float* __restrict__ Y,
                                                const float* __restrict__ Ua,
                                                const float* __restrict__ Ub,
                                                float* __restrict__ assign_out,
                                                int Kc) {
  __shared__ float sb[256];
  __shared__ float svals[256];
  __shared__ int sidx[256];
  int row = blockIdx.x, tid = threadIdx.x;
  float* ya = Y + (size_t)row * Kc;
  float l[4], s[4];
  float lm = -3.4e38f;
  #pragma unroll
  for (int j = 0; j < 4; ++j) {
    int k = j * 256 + tid;
    l[j] = ya[k];
    float u = Ua[(size_t)row * Kc + k];
    u = u * (1.0f - 2e-6f) + 1e-6f;
    float g = -logf(-logf(u));
    s[j] = (l[j] + g) * 2.0f;
    lm = fmaxf(lm, s[j]);
  }
  float m = bmax(lm, sb);
  float e[4]; float sum = 0.0f;
  #pragma unroll
  for (int j = 0; j < 4; ++j) { e[j] = expf(s[j] - m); sum += e[j]; }
  sum = bsum(sum, sb);
  #pragma unroll
  for (int j = 0; j < 4; ++j) ya[j * 256 + tid] = e[j] / sum;

  if (Ub != nullptr) {
    float bv = -3.4e38f; int bi = 0x7fffffff;
    #pragma unroll
    for (int j = 0; j < 4; ++j) {
      int k = j * 256 + tid;
      float u = Ub[(size_t)row * Kc + k];
      u = u * (1.0f - 2e-6f) + 1e-6f;
      float g = -logf(-logf(u));
      float t = l[j] + g;
      if (t > bv || (t == bv && k < bi)) { bv = t; bi = k; }
    }
    svals[tid] = bv; sidx[tid] = bi; __syncthreads();
    for (int st = 128; st > 0; st >>= 1) {
      if (tid < st) {
        if (svals[tid + st] > svals[tid] ||
            (svals[tid + st] == svals[tid] && sidx[tid + st] < sidx[tid])) {
          svals[tid] = svals[tid + st]; sidx[tid] = sidx[tid + st];
        }
      }
      __syncthreads();
    }
    if (tid == 0) assign_out[row] = (float)sidx[0];
  }
}

// bf16-MFMA GEMM-NT with exp-sum epilogue (see header comment in prose above)
__global__ __launch_bounds__(256) void k_lse_mfma(const short* __restrict__ A,
                                                  const short* __restrict__ Bm,
                                                  float* __restrict__ sumexp) {
  __shared__ short lds[16384];
  const int tid = threadIdx.x;
  const int lane = tid & 63, wv = tid >> 6;
  const int wr = wv >> 1, wc = wv & 1;
  const int row0 = blockIdx.y * 128;
  const int col0 = blockIdx.x * 128;
  f32x4_t acc[4][4];
  #pragma unroll
  for (int i = 0; i < 4; ++i)
    #pragma unroll
    for (int j = 0; j < 4; ++j)
      acc[i][j] = (f32x4_t){0.f, 0.f, 0.f, 0.f};

  for (int kt = 0; kt < 4; ++kt) {
    const int k0 = kt * 64;
    #pragma unroll
    for (int t = 0; t < 4; ++t) {
      const int c = wv * 4 + t;
      const int L = c * 1024 + lane * 16;
      const int r = L >> 7;
      const int sl = (L >> 4) & 7;
      const int ss = sl ^ (r & 7);
      const short* ga = A + (size_t)(row0 + r) * 256 + k0 + ss * 8;
      const short* gb = Bm + (size_t)(col0 + r) * 256 + k0 + ss * 8;
      __builtin_amdgcn_global_load_lds(
          (const __attribute__((address_space(1))) unsigned int*)ga,
          (__attribute__((address_space(3))) unsigned int*)&lds[c * 512], 16, 0, 0);
      __builtin_amdgcn_global_load_lds(
          (const __attribute__((address_space(1))) unsigned int*)gb,
          (__attribute__((address_space(3))) unsigned int*)&lds[8192 + c * 512], 16, 0, 0);
    }
    __syncthreads();
    #pragma unroll
    for (int s = 0; s < 2; ++s) {
      short8_t af[4], bf[4];
      const int sl = s * 4 + (lane >> 4);
      #pragma unroll
      for (int m = 0; m < 4; ++m) {
        const int r = wr * 64 + m * 16 + (lane & 15);
        af[m] = *(const short8_t*)&lds[r * 64 + (sl ^ (r & 7)) * 8];
      }
      #pragma unroll
      for (int n = 0; n < 4; ++n) {
        const int r = wc * 64 + n * 16 + (lane & 15);
        bf[n] = *(const short8_t*)&lds[8192 + r * 64 + (sl ^ (r & 7)) * 8];
      }
      #pragma unroll
      for (int m = 0; m < 4; ++m)
        #pragma unroll
        for (int n = 0; n < 4; ++n)
          acc[m][n] = __builtin_amdgcn_mfma_f32_16x16x32_bf16(af[m], bf[n], acc[m][n], 0, 0, 0);
    }
    __syncthreads();
  }

  const float invT = 1.0f / 0.07f;
  #pragma unroll
  for (int m = 0; m < 4; ++m) {
    #pragma unroll
    for (int r = 0; r < 4; ++r) {
      float v = 0.0f;
      #pragma unroll
      for (int n = 0; n < 4; ++n) v += __expf(acc[m][n][r] * invT);
      v += __shfl_xor(v, 1);
      v += __shfl_xor(v, 2);
      v += __shfl_xor(v, 4);
      v += __shfl_xor(v, 8);
      if ((lane & 15) == 0) {
        const int row = row0 + wr * 64 + m * 16 + (lane >> 4) * 4 + r;
        atomicAdd(&sumexp[row], v);
      }
    }
  }
}

__global__ __launch_bounds__(256) void k_loss(const float* __restrict__ lpn,
                                              const float* __restrict__ sen, int nb,
                                              const float* __restrict__ lpk,
                                              const float* __restrict__ sek, int nk,
                                              float* __restrict__ out) {
  __shared__ float sb[256];
  int tid = threadIdx.x;
  const float invT = 1.0f / 0.07f;
  float s = 0.0f;
  for (int b = tid; b < nb; b += 256) {
    float lp = lpn[b] * invT;
    s += logf(expf(lp) + sen[b]) - lp;
  }
  float s1 = bsum(s, sb);
  s = 0.0f;
  for (int b = tid; b < nk; b += 256) {
    float lp = lpk[b] * invT;
    s += logf(expf(lp) + sek[b]) - lp;
  }
  float s2 = bsum(s, sb);
  if (tid == 0) out[0] = s1 / (float)nb + s2 / (float)nk;
}

extern "C" void kernel_launch(void* const* d_in, const int* in_sizes, int n_in,
                              void* d_out, int out_size, void* d_ws, size_t ws_size,
                              hipStream_t stream) {
  const float* x1     = (const float*)d_in[0];
  const float* x2     = (const float*)d_in[1];
  const float* W1     = (const float*)d_in[2];
  const float* W2     = (const float*)d_in[3];
  const float* c1     = (const float*)d_in[4];
  const float* c2     = (const float*)d_in[5];
  const float* qn     = (const float*)d_in[6];
  const float* qk     = (const float*)d_in[7];
  const float* u1a    = (const float*)d_in[8];
  const float* u1b    = (const float*)d_in[9];
  const float* u2a    = (const float*)d_in[10];
  const float* qnoise = (const float*)d_in[12];

  float* out_assign = (float*)d_out;
  float* out_feat2  = out_assign + B_N;
  float* out_aggk2  = out_feat2 + (size_t)B_N * D_D;
  float* out_loss   = out_aggk2 + (size_t)K_C * D_D;

  float* w = (float*)d_ws;
  float* f1     = w; w += (size_t)B_N * D_D;
  __hip_bfloat16* f1b    = (__hip_bfloat16*)w; w += (size_t)B_N * D_D / 2;
  float* ctx1n  = w; w += (size_t)K_C * D_D;
  float* ctx2n  = w; w += (size_t)K_C * D_D;
  __hip_bfloat16* qnnb   = (__hip_bfloat16*)w; w += (size_t)L_Q * D_D / 2;
  float* qkn    = w; w += (size_t)KQ_ * D_D;
  __hip_bfloat16* qcombb = (__hip_bfloat16*)w; w += (size_t)KQ_ * D_D / 2;
  float* ybuf   = w; w += (size_t)B_N * K_C;
  float* aggk1  = w; w += (size_t)K_C * D_D;
  __hip_bfloat16* aggk1b = (__hip_bfloat16*)w; w += (size_t)K_C * D_D / 2;
  float* zero0 = w;
  float* aggt1  = w; w += (size_t)K_C * D_D;
  float* aggt2  = w; w += (size_t)K_C * D_D;
  float* norm1  = w; w += K_C;
  float* norm2  = w; w += K_C;
  float* sen    = w; w += B_N;
  float* sek    = w; w += K_C;
  float* zend   = w;
  float* lpn    = w; w += B_N;
  float* lpk    = w; w += K_C;
  hipMemsetAsync(zero0, 0, (size_t)(zend - zero0) * sizeof(float), stream);

  k_gemm_nn<<<dim3(D_D / 64, B_N / 64), 256, 0, stream>>>(x1, W1, f1, B_N, D_D, D_IN);
  k_rownorm_dual<<<B_N, 256, 0, stream>>>(f1, f1, f1b);
  k_gemm_nn<<<dim3(D_D / 64, B_N / 64), 256, 0, stream>>>(x2, W2, out_feat2, B_N, D_D, D_IN);
  k_rownorm<<<B_N, 256, 0, stream>>>(out_feat2, out_feat2);

  k_rownorm<<<K_C, 256, 0, stream>>>(c1, ctx1n);
  k_rownorm<<<K_C, 256, 0, stream>>>(c2, ctx2n);
  k_rownorm_bf16<<<L_Q, 256, 0, stream>>>(qn, qnnb);
  k_rownorm<<<KQ_, 256, 0, stream>>>(qk, qkn);
  k_rownorm_comb_bf16<<<KQ_, 256, 0, stream>>>(qkn, qnoise, qcombb);

  k_gemm_nt<<<dim3(K_C / 64, B_N / 64), 256, 0, stream>>>(f1, ctx1n, ybuf, B_N, K_C, D_D);
  k_gumbel<<<B_N, 256, 0, stream>>>(ybuf, u1a, u1b, out_assign, K_C);
  k_colsum<<<dim3(K_C / 256, 16), 256, 0, stream>>>(ybuf, norm1, B_N, K_C);
  k_gemm_tn<<<dim3(D_D / 64, K_C / 64, 8), 256, 0, stream>>>(ybuf, f1, aggt1, K_C, D_D, B_N / 8);
  k_rownorm_div_dual<<<K_C, 256, 0, stream>>>(aggt1, norm1, aggk1, aggk1b);

  k_gemm_nt<<<dim3(K_C / 64, B_N / 64), 256, 0, stream>>>(out_feat2, ctx2n, ybuf, B_N, K_C, D_D);
  k_gumbel<<<B_N, 256, 0, stream>>>(ybuf, u2a, nullptr, nullptr, K_C);
  k_colsum<<<dim3(K_C / 256, 16), 256, 0, stream>>>(ybuf, norm2, B_N, K_C);
  k_gemm_tn<<<dim3(D_D / 64, K_C / 64, 8), 256, 0, stream>>>(ybuf, out_feat2, aggt2, K_C, D_D, B_N / 8);
  k_rownorm_div<<<K_C, 256, 0, stream>>>(aggt2, norm2, out_aggk2);

  k_dotrows<<<B_N, 256, 0, stream>>>(f1, out_feat2, lpn);
  k_dotrows<<<K_C, 256, 0, stream>>>(aggk1, out_aggk2, lpk);

  k_lse_mfma<<<dim3(L_Q / 128, B_N / 128), 256, 0, stream>>>((const short*)f1b, (const short*)qnnb, sen);
  k_lse_mfma<<<dim3(KQ_ / 128, K_C / 128), 256, 0, stream>>>((const short*)aggk1b, (const short*)qcombb, sek);

  k_loss<<<1, 256, 0, stream>>>(lpn, sen, B_N, lpk, sek, K_C, out_loss);
}

// Round 4
// 780.666 us; speedup vs baseline: 1.9832x; 1.2469x over previous
//
#include <hip/hip_runtime.h>
#include <hip/hip_bf16.h>
#include <math.h>

#define B_N  4096
#define D_IN 1024
#define D_D  256
#define K_C  1024
#define L_Q  32768
#define KQ_  4096

typedef __attribute__((ext_vector_type(8))) short short8_t;
typedef __attribute__((ext_vector_type(4))) float f32x4_t;

__device__ __forceinline__ float bsum(float v, float* sb) {
  int t = threadIdx.x;
  sb[t] = v; __syncthreads();
  #pragma unroll
  for (int s = 128; s > 0; s >>= 1) {
    if (t < s) sb[t] += sb[t + s];
    __syncthreads();
  }
  float r = sb[0]; __syncthreads();
  return r;
}

__device__ __forceinline__ float bmax(float v, float* sb) {
  int t = threadIdx.x;
  sb[t] = v; __syncthreads();
  #pragma unroll
  for (int s = 128; s > 0; s >>= 1) {
    if (t < s) sb[t] = fmaxf(sb[t], sb[t + s]);
    __syncthreads();
  }
  float r = sb[0]; __syncthreads();
  return r;
}

__global__ __launch_bounds__(256) void k_rownorm(const float* __restrict__ src,
                                                 float* __restrict__ dst) {
  __shared__ float sb[256];
  int row = blockIdx.x, tid = threadIdx.x;
  float v = src[(size_t)row * 256 + tid];
  float ss = bsum(v * v, sb);
  dst[(size_t)row * 256 + tid] = v * rsqrtf(fmaxf(ss, 1e-12f));
}

__global__ __launch_bounds__(256) void k_rownorm_bf16(const float* __restrict__ src,
                                                      __hip_bfloat16* __restrict__ dst) {
  __shared__ float sb[256];
  int row = blockIdx.x, tid = threadIdx.x;
  float v = src[(size_t)row * 256 + tid];
  float ss = bsum(v * v, sb);
  dst[(size_t)row * 256 + tid] = __float2bfloat16(v * rsqrtf(fmaxf(ss, 1e-12f)));
}

__global__ __launch_bounds__(256) void k_rownorm_dual(const float* __restrict__ src,
                                                      float* __restrict__ dstf,
                                                      __hip_bfloat16* __restrict__ dstb) {
  __shared__ float sb[256];
  int row = blockIdx.x, tid = threadIdx.x;
  float v = src[(size_t)row * 256 + tid];
  float ss = bsum(v * v, sb);
  float o = v * rsqrtf(fmaxf(ss, 1e-12f));
  dstf[(size_t)row * 256 + tid] = o;
  dstb[(size_t)row * 256 + tid] = __float2bfloat16(o);
}

__global__ __launch_bounds__(256) void k_rownorm_comb_bf16(const float* __restrict__ a,
                                                           const float* __restrict__ b,
                                                           __hip_bfloat16* __restrict__ dst) {
  __shared__ float sb[256];
  int row = blockIdx.x, tid = threadIdx.x;
  size_t i = (size_t)row * 256 + tid;
  float v = 2.0f * a[i] + b[i];
  float ss = bsum(v * v, sb);
  dst[i] = __float2bfloat16(v * rsqrtf(fmaxf(ss, 1e-12f)));
}

__global__ __launch_bounds__(256) void k_rownorm_div(const float* __restrict__ src,
                                                     const float* __restrict__ norm,
                                                     float* __restrict__ dst) {
  __shared__ float sb[256];
  int row = blockIdx.x, tid = threadIdx.x;
  size_t i = (size_t)row * 256 + tid;
  float v = src[i] / (norm[row] + 1e-8f);
  float ss = bsum(v * v, sb);
  dst[i] = v * rsqrtf(fmaxf(ss, 1e-12f));
}

__global__ __launch_bounds__(256) void k_rownorm_div_dual(const float* __restrict__ src,
                                                          const float* __restrict__ norm,
                                                          float* __restrict__ dstf,
                                                          __hip_bfloat16* __restrict__ dstb) {
  __shared__ float sb[256];
  int row = blockIdx.x, tid = threadIdx.x;
  size_t i = (size_t)row * 256 + tid;
  float v = src[i] / (norm[row] + 1e-8f);
  float ss = bsum(v * v, sb);
  float o = v * rsqrtf(fmaxf(ss, 1e-12f));
  dstf[i] = o;
  dstb[i] = __float2bfloat16(o);
}

__global__ __launch_bounds__(256) void k_dotrows(const float* __restrict__ a,
                                                 const float* __restrict__ b,
                                                 float* __restrict__ out) {
  __shared__ float sb[256];
  int row = blockIdx.x, tid = threadIdx.x;
  size_t i = (size_t)row * 256 + tid;
  float s = bsum(a[i] * b[i], sb);
  if (tid == 0) out[row] = s;
}

__global__ __launch_bounds__(256) void k_gemm_nn(const float* __restrict__ A,
                                                 const float* __restrict__ Bm,
                                                 float* __restrict__ C,
                                                 int M, int N, int K) {
  __shared__ float As[16][68];
  __shared__ float Bs[16][68];
  const int tid = threadIdx.x;
  const int tx = tid & 15, ty = tid >> 4;
  const int bx = blockIdx.x, by = blockIdx.y;
  const int ar = tid >> 2, ac4 = (tid & 3) << 2;
  const int br = tid >> 4, bc4 = (tid & 15) << 2;
  float acc[4][4] = {};
  const float* Ap = A + (size_t)(by * 64 + ar) * K + ac4;
  const float* Bp = Bm + (size_t)br * N + bx * 64 + bc4;
  for (int k0 = 0; k0 < K; k0 += 16) {
    float4 av = *(const float4*)(Ap + k0);
    As[ac4 + 0][ar] = av.x; As[ac4 + 1][ar] = av.y;
    As[ac4 + 2][ar] = av.z; As[ac4 + 3][ar] = av.w;
    *(float4*)&Bs[br][bc4] = *(const float4*)(Bp + (size_t)k0 * N);
    __syncthreads();
    #pragma unroll
    for (int kk = 0; kk < 16; ++kk) {
      float4 a = *(const float4*)&As[kk][ty << 2];
      float4 b = *(const float4*)&Bs[kk][tx << 2];
      float af[4] = {a.x, a.y, a.z, a.w};
      float bf[4] = {b.x, b.y, b.z, b.w};
      #pragma unroll
      for (int i = 0; i < 4; ++i)
        #pragma unroll
        for (int j = 0; j < 4; ++j)
          acc[i][j] = fmaf(af[i], bf[j], acc[i][j]);
    }
    __syncthreads();
  }
  float* Cp = C + (size_t)(by * 64 + (ty << 2)) * N + bx * 64 + (tx << 2);
  #pragma unroll
  for (int i = 0; i < 4; ++i) {
    float4 o = make_float4(acc[i][0], acc[i][1], acc[i][2], acc[i][3]);
    *(float4*)(Cp + (size_t)i * N) = o;
  }
}

__global__ __launch_bounds__(256) void k_gemm_nt(const float* __restrict__ A,
                                                 const float* __restrict__ Bm,
                                                 float* __restrict__ C,
                                                 int M, int N, int K) {
  __shared__ float As[16][68];
  __shared__ float Bs[16][68];
  const int tid = threadIdx.x;
  const int tx = tid & 15, ty = tid >> 4;
  const int bx = blockIdx.x, by = blockIdx.y;
  const int lr = tid >> 2, lc4 = (tid & 3) << 2;
  float acc[4][4] = {};
  const float* Ap = A + (size_t)(by * 64 + lr) * K + lc4;
  const float* Bp = Bm + (size_t)(bx * 64 + lr) * K + lc4;
  for (int k0 = 0; k0 < K; k0 += 16) {
    float4 av = *(const float4*)(Ap + k0);
    As[lc4 + 0][lr] = av.x; As[lc4 + 1][lr] = av.y;
    As[lc4 + 2][lr] = av.z; As[lc4 + 3][lr] = av.w;
    float4 bv = *(const float4*)(Bp + k0);
    Bs[lc4 + 0][lr] = bv.x; Bs[lc4 + 1][lr] = bv.y;
    Bs[lc4 + 2][lr] = bv.z; Bs[lc4 + 3][lr] = bv.w;
    __syncthreads();
    #pragma unroll
    for (int kk = 0; kk < 16; ++kk) {
      float4 a = *(const float4*)&As[kk][ty << 2];
      float4 b = *(const float4*)&Bs[kk][tx << 2];
      float af[4] = {a.x, a.y, a.z, a.w};
      float bf[4] = {b.x, b.y, b.z, b.w};
      #pragma unroll
      for (int i = 0; i < 4; ++i)
        #pragma unroll
        for (int j = 0; j < 4; ++j)
          acc[i][j] = fmaf(af[i], bf[j], acc[i][j]);
    }
    __syncthreads();
  }
  float* Cp = C + (size_t)(by * 64 + (ty << 2)) * N + bx * 64 + (tx << 2);
  #pragma unroll
  for (int i = 0; i < 4; ++i) {
    float4 o = make_float4(acc[i][0], acc[i][1], acc[i][2], acc[i][3]);
    *(float4*)(Cp + (size_t)i * N) = o;
  }
}

__global__ __launch_bounds__(256) void k_gemm_tn(const float* __restrict__ Y,
                                                 const float* __restrict__ F,
                                                 float* __restrict__ C,
                                                 int Kc, int Dd, int chunk) {
  __shared__ float As[16][68];
  __shared__ float Bs[16][68];
  const int tid = threadIdx.x;
  const int tx = tid & 15, ty = tid >> 4;
  const int bx = blockIdx.x, by = blockIdx.y, bz = blockIdx.z;
  const int lr = tid >> 4, lc4 = (tid & 15) << 2;
  float acc[4][4] = {};
  const int b0 = bz * chunk;
  for (int bb = b0; bb < b0 + chunk; bb += 16) {
    *(float4*)&As[lr][lc4] = *(const float4*)(Y + (size_t)(bb + lr) * Kc + by * 64 + lc4);
    *(float4*)&Bs[lr][lc4] = *(const float4*)(F + (size_t)(bb + lr) * Dd + bx * 64 + lc4);
    __syncthreads();
    #pragma unroll
    for (int kk = 0; kk < 16; ++kk) {
      float4 a = *(const float4*)&As[kk][ty << 2];
      float4 b = *(const float4*)&Bs[kk][tx << 2];
      float af[4] = {a.x, a.y, a.z, a.w};
      float bf[4] = {b.x, b.y, b.z, b.w};
      #pragma unroll
      for (int i = 0; i < 4; ++i)
        #pragma unroll
        for (int j = 0; j < 4; ++j)
          acc[i][j] = fmaf(af[i], bf[j], acc[i][j]);
    }
    __syncthreads();
  }
  #pragma unroll
  for (int i = 0; i < 4; ++i)
    #pragma unroll
    for (int j = 0; j < 4; ++j)
      atomicAdd(&C[(size_t)(by * 64 + (ty << 2) + i) * Dd + bx * 64 + (tx << 2) + j],
                acc[i][j]);
}

__global__ __launch_bounds__(256) void k_colsum(const float* __restrict__ Y,
                                                float* __restrict__ norm,
                                                int Bb, int Kc) {
  int k = blockIdx.x * 256 + threadIdx.x;
  int chunk = Bb / gridDim.y;
  int b0 = blockIdx.y * chunk;
  float s = 0.0f;
  for (int b = b0; b < b0 + chunk; ++b) s += Y[(size_t)b * Kc + k];
  atomicAdd(&norm[k], s);
}

__global__ __launch_bounds__(256) void k_gumbel(float* __restrict__ Y,
                                                const float* __restrict__ Ua,
                                                const float* __restrict__ Ub,
                                                float* __restrict__ assign_out,
                                                int Kc) {
  __shared__ float sb[256];
  __shared__ float svals[256];
  __shared__ int sidx[256];
  int row = blockIdx.x, tid = threadIdx.x;
  float* ya = Y + (size_t)row * Kc;
  float l[4], s[4];
  float lm = -3.4e38f;
  #pragma unroll
  for (int j = 0; j < 4; ++j) {
    int k = j * 256 + tid;
    l[j] = ya[k];
    float u = Ua[(size_t)row * Kc + k];
    u = u * (1.0f - 2e-6f) + 1e-6f;
    float g = -__logf(-__logf(u));
    s[j] = (l[j] + g) * 2.0f;
    lm = fmaxf(lm, s[j]);
  }
  float m = bmax(lm, sb);
  float e[4]; float sum = 0.0f;
  #pragma unroll
  for (int j = 0; j < 4; ++j) { e[j] = __expf(s[j] - m); sum += e[j]; }
  sum = bsum(sum, sb);
  #pragma unroll
  for (int j = 0; j < 4; ++j) ya[j * 256 + tid] = e[j] / sum;

  if (Ub != nullptr) {
    float bv = -3.4e38f; int bi = 0x7fffffff;
    #pragma unroll
    for (int j = 0; j < 4; ++j) {
      int k = j * 256 + tid;
      float u = Ub[(size_t)row * Kc + k];
      u = u * (1.0f - 2e-6f) + 1e-6f;
      float g = -__logf(-__logf(u));
      float t = l[j] + g;
      if (t > bv || (t == bv && k < bi)) { bv = t; bi = k; }
    }
    svals[tid] = bv; sidx[tid] = bi; __syncthreads();
    for (int st = 128; st > 0; st >>= 1) {
      if (tid < st) {
        if (svals[tid + st] > svals[tid] ||
            (svals[tid + st] == svals[tid] && sidx[tid + st] < sidx[tid])) {
          svals[tid] = svals[tid + st]; sidx[tid] = sidx[tid + st];
        }
      }
      __syncthreads();
    }
    if (tid == 0) assign_out[row] = (float)sidx[0];
  }
}

// ======================= persistent-column bf16-MFMA LSE =======================
// sumexp[row] += sum_cols exp(dot(A[row],B[col])/TEMP).
// Grid (8 chunks, M/128). chunk == blockIdx.x == XCD id (round-robin dispatch),
// so all blocks of a chunk share one XCD's L2 for their B slice.
// A fragments hoisted to registers (a[4][8], K=256); B tiles (128 cols x 256)
// double-buffered in LDS (2 x 64 KB), staged via global_load_lds with the
// both-sides XOR slot swizzle (linear LDS dest, inverse-swizzled global src,
// swizzled ds_read). Exp-sums accumulate in registers; 1 atomic/row/block.
#define LSE_TILE_SHORTS 32768  // 128 cols * 256 K

__device__ __forceinline__ void lse_stage(const short* __restrict__ Bm,
                                          short* dst, int colb, int tid) {
  const int rbase = tid >> 5;   // dest row = p*8 + rbase (512 B rows)
  const int sl = tid & 31;      // dest 16B slot within row
  #pragma unroll
  for (int p = 0; p < 16; ++p) {
    const int r = p * 8 + rbase;
    const int ss = sl ^ (r & 7);  // inverse-swizzled source slot
    const short* g = Bm + (size_t)(colb + r) * 256 + ss * 8;
    __builtin_amdgcn_global_load_lds(
        (const __attribute__((address_space(1))) unsigned int*)g,
        (__attribute__((address_space(3))) unsigned int*)(dst + p * 2048 + tid * 8),
        16, 0, 0);
  }
}

__global__ __launch_bounds__(256, 1) void k_lse2(const short* __restrict__ A,
                                                 const short* __restrict__ Bm,
                                                 float* __restrict__ sumexp,
                                                 int colsPerChunk) {
  __shared__ short lds[2 * LSE_TILE_SHORTS];  // 128 KB
  const int tid = threadIdx.x;
  const int lane = tid & 63, wv = tid >> 6;
  const int wr = wv >> 1, wc = wv & 1;        // 2x2 wave grid, 64x64 per wave
  const int row0 = blockIdx.y * 128;
  const int col0 = blockIdx.x * colsPerChunk;
  const int ntiles = colsPerChunk >> 7;
  const int g = lane >> 4;

  // hoist A fragments: rows wr*64 + m*16 + (lane&15), k-step k covers K [k*32,(k+1)*32)
  short8_t a[4][8];
  #pragma unroll
  for (int m = 0; m < 4; ++m) {
    const size_t rbase = (size_t)(row0 + wr * 64 + m * 16 + (lane & 15)) * 256;
    #pragma unroll
    for (int k = 0; k < 8; ++k)
      a[m][k] = *(const short8_t*)&A[rbase + k * 32 + g * 8];
  }

  float rsum[4][4];
  #pragma unroll
  for (int m = 0; m < 4; ++m)
    #pragma unroll
    for (int r = 0; r < 4; ++r) rsum[m][r] = 0.0f;

  lse_stage(Bm, lds, col0, tid);
  __syncthreads();

  const float invT = 1.0f / 0.07f;
  int cur = 0;
  for (int t = 0; t < ntiles; ++t) {
    if (t + 1 < ntiles)
      lse_stage(Bm, lds + (cur ^ 1) * LSE_TILE_SHORTS, col0 + (t + 1) * 128, tid);

    const short* Bt = lds + cur * LSE_TILE_SHORTS;
    f32x4_t acc[4][4];
    #pragma unroll
    for (int m = 0; m < 4; ++m)
      #pragma unroll
      for (int n = 0; n < 4; ++n)
        acc[m][n] = (f32x4_t){0.f, 0.f, 0.f, 0.f};

    #pragma unroll
    for (int k = 0; k < 8; ++k) {
      short8_t bf[4];
      #pragma unroll
      for (int n = 0; n < 4; ++n) {
        const int r = wc * 64 + n * 16 + (lane & 15);
        bf[n] = *(const short8_t*)&Bt[r * 256 + (((k * 4 + g) ^ (r & 7)) * 8)];
      }
      #pragma unroll
      for (int m = 0; m < 4; ++m)
        #pragma unroll
        for (int n = 0; n < 4; ++n)
          acc[m][n] = __builtin_amdgcn_mfma_f32_16x16x32_bf16(a[m][k], bf[n], acc[m][n], 0, 0, 0);
    }

    // per-tile epilogue: exp and accumulate into register row-sums
    #pragma unroll
    for (int m = 0; m < 4; ++m)
      #pragma unroll
      for (int r = 0; r < 4; ++r) {
        float v = __expf(acc[m][0][r] * invT) + __expf(acc[m][1][r] * invT) +
                  __expf(acc[m][2][r] * invT) + __expf(acc[m][3][r] * invT);
        rsum[m][r] += v;
      }

    __syncthreads();
    cur ^= 1;
  }

  // final: reduce over the 16 lanes of each group, one atomic per row
  #pragma unroll
  for (int m = 0; m < 4; ++m)
    #pragma unroll
    for (int r = 0; r < 4; ++r) {
      float v = rsum[m][r];
      v += __shfl_xor(v, 1);
      v += __shfl_xor(v, 2);
      v += __shfl_xor(v, 4);
      v += __shfl_xor(v, 8);
      if ((lane & 15) == 0)
        atomicAdd(&sumexp[row0 + wr * 64 + m * 16 + g * 4 + r], v);
    }
}

__global__ __launch_bounds__(256) void k_loss(const float* __restrict__ lpn,
                                              const float* __restrict__ sen, int nb,
                                              const float* __restrict__ lpk,
                                              const float* __restrict__ sek, int nk,
                                              float* __restrict__ out) {
  __shared__ float sb[256];
  int tid = threadIdx.x;
  const float invT = 1.0f / 0.07f;
  float s = 0.0f;
  for (int b = tid; b < nb; b += 256) {
    float lp = lpn[b] * invT;
    s += logf(expf(lp) + sen[b]) - lp;
  }
  float s1 = bsum(s, sb);
  s = 0.0f;
  for (int b = tid; b < nk; b += 256) {
    float lp = lpk[b] * invT;
    s += logf(expf(lp) + sek[b]) - lp;
  }
  float s2 = bsum(s, sb);
  if (tid == 0) out[0] = s1 / (float)nb + s2 / (float)nk;
}

extern "C" void kernel_launch(void* const* d_in, const int* in_sizes, int n_in,
                              void* d_out, int out_size, void* d_ws, size_t ws_size,
                              hipStream_t stream) {
  const float* x1     = (const float*)d_in[0];
  const float* x2     = (const float*)d_in[1];
  const float* W1     = (const float*)d_in[2];
  const float* W2     = (const float*)d_in[3];
  const float* c1     = (const float*)d_in[4];
  const float* c2     = (const float*)d_in[5];
  const float* qn     = (const float*)d_in[6];
  const float* qk     = (const float*)d_in[7];
  const float* u1a    = (const float*)d_in[8];
  const float* u1b    = (const float*)d_in[9];
  const float* u2a    = (const float*)d_in[10];
  const float* qnoise = (const float*)d_in[12];

  float* out_assign = (float*)d_out;
  float* out_feat2  = out_assign + B_N;
  float* out_aggk2  = out_feat2 + (size_t)B_N * D_D;
  float* out_loss   = out_aggk2 + (size_t)K_C * D_D;

  float* w = (float*)d_ws;
  float* f1     = w; w += (size_t)B_N * D_D;
  __hip_bfloat16* f1b    = (__hip_bfloat16*)w; w += (size_t)B_N * D_D / 2;
  float* ctx1n  = w; w += (size_t)K_C * D_D;
  float* ctx2n  = w; w += (size_t)K_C * D_D;
  __hip_bfloat16* qnnb   = (__hip_bfloat16*)w; w += (size_t)L_Q * D_D / 2;
  float* qkn    = w; w += (size_t)KQ_ * D_D;
  __hip_bfloat16* qcombb = (__hip_bfloat16*)w; w += (size_t)KQ_ * D_D / 2;
  float* ybuf   = w; w += (size_t)B_N * K_C;
  float* aggk1  = w; w += (size_t)K_C * D_D;
  __hip_bfloat16* aggk1b = (__hip_bfloat16*)w; w += (size_t)K_C * D_D / 2;
  float* zero0 = w;
  float* aggt1  = w; w += (size_t)K_C * D_D;
  float* aggt2  = w; w += (size_t)K_C * D_D;
  float* norm1  = w; w += K_C;
  float* norm2  = w; w += K_C;
  float* sen    = w; w += B_N;
  float* sek    = w; w += K_C;
  float* zend   = w;
  float* lpn    = w; w += B_N;
  float* lpk    = w; w += K_C;
  hipMemsetAsync(zero0, 0, (size_t)(zend - zero0) * sizeof(float), stream);

  k_gemm_nn<<<dim3(D_D / 64, B_N / 64), 256, 0, stream>>>(x1, W1, f1, B_N, D_D, D_IN);
  k_rownorm_dual<<<B_N, 256, 0, stream>>>(f1, f1, f1b);
  k_gemm_nn<<<dim3(D_D / 64, B_N / 64), 256, 0, stream>>>(x2, W2, out_feat2, B_N, D_D, D_IN);
  k_rownorm<<<B_N, 256, 0, stream>>>(out_feat2, out_feat2);

  k_rownorm<<<K_C, 256, 0, stream>>>(c1, ctx1n);
  k_rownorm<<<K_C, 256, 0, stream>>>(c2, ctx2n);
  k_rownorm_bf16<<<L_Q, 256, 0, stream>>>(qn, qnnb);
  k_rownorm<<<KQ_, 256, 0, stream>>>(qk, qkn);
  k_rownorm_comb_bf16<<<KQ_, 256, 0, stream>>>(qkn, qnoise, qcombb);

  k_gemm_nt<<<dim3(K_C / 64, B_N / 64), 256, 0, stream>>>(f1, ctx1n, ybuf, B_N, K_C, D_D);
  k_gumbel<<<B_N, 256, 0, stream>>>(ybuf, u1a, u1b, out_assign, K_C);
  k_colsum<<<dim3(K_C / 256, 16), 256, 0, stream>>>(ybuf, norm1, B_N, K_C);
  k_gemm_tn<<<dim3(D_D / 64, K_C / 64, 8), 256, 0, stream>>>(ybuf, f1, aggt1, K_C, D_D, B_N / 8);
  k_rownorm_div_dual<<<K_C, 256, 0, stream>>>(aggt1, norm1, aggk1, aggk1b);

  k_gemm_nt<<<dim3(K_C / 64, B_N / 64), 256, 0, stream>>>(out_feat2, ctx2n, ybuf, B_N, K_C, D_D);
  k_gumbel<<<B_N, 256, 0, stream>>>(ybuf, u2a, nullptr, nullptr, K_C);
  k_colsum<<<dim3(K_C / 256, 16), 256, 0, stream>>>(ybuf, norm2, B_N, K_C);
  k_gemm_tn<<<dim3(D_D / 64, K_C / 64, 8), 256, 0, stream>>>(ybuf, out_feat2, aggt2, K_C, D_D, B_N / 8);
  k_rownorm_div<<<K_C, 256, 0, stream>>>(aggt2, norm2, out_aggk2);

  k_dotrows<<<B_N, 256, 0, stream>>>(f1, out_feat2, lpn);
  k_dotrows<<<K_C, 256, 0, stream>>>(aggk1, out_aggk2, lpk);

  // persistent-column LSE: grid (8 chunks == XCDs, rows/128)
  k_lse2<<<dim3(8, B_N / 128), 256, 0, stream>>>((const short*)f1b, (const short*)qnnb, sen, L_Q / 8);
  k_lse2<<<dim3(8, K_C / 128), 256, 0, stream>>>((const short*)aggk1b, (const short*)qcombb, sek, KQ_ / 8);

  k_loss<<<1, 256, 0, stream>>>(lpn, sen, B_N, lpk, sek, K_C, out_loss);
}

// Round 6
// 761.567 us; speedup vs baseline: 2.0329x; 1.0251x over previous
//
#include <hip/hip_runtime.h>
#include <hip/hip_bf16.h>
#include <math.h>

#define B_N  4096
#define D_IN 1024
#define D_D  256
#define K_C  1024
#define L_Q  32768
#define KQ_  4096

typedef __attribute__((ext_vector_type(8))) short short8_t;
typedef __attribute__((ext_vector_type(4))) float f32x4_t;

__device__ __forceinline__ float bsum(float v, float* sb) {
  int t = threadIdx.x;
  sb[t] = v; __syncthreads();
  #pragma unroll
  for (int s = 128; s > 0; s >>= 1) {
    if (t < s) sb[t] += sb[t + s];
    __syncthreads();
  }
  float r = sb[0]; __syncthreads();
  return r;
}

__device__ __forceinline__ float bmax(float v, float* sb) {
  int t = threadIdx.x;
  sb[t] = v; __syncthreads();
  #pragma unroll
  for (int s = 128; s > 0; s >>= 1) {
    if (t < s) sb[t] = fmaxf(sb[t], sb[t + s]);
    __syncthreads();
  }
  float r = sb[0]; __syncthreads();
  return r;
}

__global__ __launch_bounds__(256) void k_rownorm(const float* __restrict__ src,
                                                 float* __restrict__ dst) {
  __shared__ float sb[256];
  int row = blockIdx.x, tid = threadIdx.x;
  float v = src[(size_t)row * 256 + tid];
  float ss = bsum(v * v, sb);
  dst[(size_t)row * 256 + tid] = v * rsqrtf(fmaxf(ss, 1e-12f));
}

__global__ __launch_bounds__(256) void k_rownorm_bf16(const float* __restrict__ src,
                                                      __hip_bfloat16* __restrict__ dst) {
  __shared__ float sb[256];
  int row = blockIdx.x, tid = threadIdx.x;
  float v = src[(size_t)row * 256 + tid];
  float ss = bsum(v * v, sb);
  dst[(size_t)row * 256 + tid] = __float2bfloat16(v * rsqrtf(fmaxf(ss, 1e-12f)));
}

__global__ __launch_bounds__(256) void k_rownorm_dual(const float* __restrict__ src,
                                                      float* __restrict__ dstf,
                                                      __hip_bfloat16* __restrict__ dstb) {
  __shared__ float sb[256];
  int row = blockIdx.x, tid = threadIdx.x;
  float v = src[(size_t)row * 256 + tid];
  float ss = bsum(v * v, sb);
  float o = v * rsqrtf(fmaxf(ss, 1e-12f));
  dstf[(size_t)row * 256 + tid] = o;
  dstb[(size_t)row * 256 + tid] = __float2bfloat16(o);
}

__global__ __launch_bounds__(256) void k_rownorm_comb_bf16(const float* __restrict__ a,
                                                           const float* __restrict__ b,
                                                           __hip_bfloat16* __restrict__ dst) {
  __shared__ float sb[256];
  int row = blockIdx.x, tid = threadIdx.x;
  size_t i = (size_t)row * 256 + tid;
  float v = 2.0f * a[i] + b[i];
  float ss = bsum(v * v, sb);
  dst[i] = __float2bfloat16(v * rsqrtf(fmaxf(ss, 1e-12f)));
}

__global__ __launch_bounds__(256) void k_rownorm_div(const float* __restrict__ src,
                                                     const float* __restrict__ norm,
                                                     float* __restrict__ dst) {
  __shared__ float sb[256];
  int row = blockIdx.x, tid = threadIdx.x;
  size_t i = (size_t)row * 256 + tid;
  float v = src[i] / (norm[row] + 1e-8f);
  float ss = bsum(v * v, sb);
  dst[i] = v * rsqrtf(fmaxf(ss, 1e-12f));
}

__global__ __launch_bounds__(256) void k_rownorm_div_dual(const float* __restrict__ src,
                                                          const float* __restrict__ norm,
                                                          float* __restrict__ dstf,
                                                          __hip_bfloat16* __restrict__ dstb) {
  __shared__ float sb[256];
  int row = blockIdx.x, tid = threadIdx.x;
  size_t i = (size_t)row * 256 + tid;
  float v = src[i] / (norm[row] + 1e-8f);
  float ss = bsum(v * v, sb);
  float o = v * rsqrtf(fmaxf(ss, 1e-12f));
  dstf[i] = o;
  dstb[i] = __float2bfloat16(o);
}

__global__ __launch_bounds__(256) void k_dotrows(const float* __restrict__ a,
                                                 const float* __restrict__ b,
                                                 float* __restrict__ out) {
  __shared__ float sb[256];
  int row = blockIdx.x, tid = threadIdx.x;
  size_t i = (size_t)row * 256 + tid;
  float s = bsum(a[i] * b[i], sb);
  if (tid == 0) out[row] = s;
}

__global__ __launch_bounds__(256) void k_gemm_nn(const float* __restrict__ A,
                                                 const float* __restrict__ Bm,
                                                 float* __restrict__ C,
                                                 int M, int N, int K) {
  __shared__ float As[16][68];
  __shared__ float Bs[16][68];
  const int tid = threadIdx.x;
  const int tx = tid & 15, ty = tid >> 4;
  const int bx = blockIdx.x, by = blockIdx.y;
  const int ar = tid >> 2, ac4 = (tid & 3) << 2;
  const int br = tid >> 4, bc4 = (tid & 15) << 2;
  float acc[4][4] = {};
  const float* Ap = A + (size_t)(by * 64 + ar) * K + ac4;
  const float* Bp = Bm + (size_t)br * N + bx * 64 + bc4;
  for (int k0 = 0; k0 < K; k0 += 16) {
    float4 av = *(const float4*)(Ap + k0);
    As[ac4 + 0][ar] = av.x; As[ac4 + 1][ar] = av.y;
    As[ac4 + 2][ar] = av.z; As[ac4 + 3][ar] = av.w;
    *(float4*)&Bs[br][bc4] = *(const float4*)(Bp + (size_t)k0 * N);
    __syncthreads();
    #pragma unroll
    for (int kk = 0; kk < 16; ++kk) {
      float4 a = *(const float4*)&As[kk][ty << 2];
      float4 b = *(const float4*)&Bs[kk][tx << 2];
      float af[4] = {a.x, a.y, a.z, a.w};
      float bf[4] = {b.x, b.y, b.z, b.w};
      #pragma unroll
      for (int i = 0; i < 4; ++i)
        #pragma unroll
        for (int j = 0; j < 4; ++j)
          acc[i][j] = fmaf(af[i], bf[j], acc[i][j]);
    }
    __syncthreads();
  }
  float* Cp = C + (size_t)(by * 64 + (ty << 2)) * N + bx * 64 + (tx << 2);
  #pragma unroll
  for (int i = 0; i < 4; ++i) {
    float4 o = make_float4(acc[i][0], acc[i][1], acc[i][2], acc[i][3]);
    *(float4*)(Cp + (size_t)i * N) = o;
  }
}

__global__ __launch_bounds__(256) void k_gemm_nt(const float* __restrict__ A,
                                                 const float* __restrict__ Bm,
                                                 float* __restrict__ C,
                                                 int M, int N, int K) {
  __shared__ float As[16][68];
  __shared__ float Bs[16][68];
  const int tid = threadIdx.x;
  const int tx = tid & 15, ty = tid >> 4;
  const int bx = blockIdx.x, by = blockIdx.y;
  const int lr = tid >> 2, lc4 = (tid & 3) << 2;
  float acc[4][4] = {};
  const float* Ap = A + (size_t)(by * 64 + lr) * K + lc4;
  const float* Bp = Bm + (size_t)(bx * 64 + lr) * K + lc4;
  for (int k0 = 0; k0 < K; k0 += 16) {
    float4 av = *(const float4*)(Ap + k0);
    As[lc4 + 0][lr] = av.x; As[lc4 + 1][lr] = av.y;
    As[lc4 + 2][lr] = av.z; As[lc4 + 3][lr] = av.w;
    float4 bv = *(const float4*)(Bp + k0);
    Bs[lc4 + 0][lr] = bv.x; Bs[lc4 + 1][lr] = bv.y;
    Bs[lc4 + 2][lr] = bv.z; Bs[lc4 + 3][lr] = bv.w;
    __syncthreads();
    #pragma unroll
    for (int kk = 0; kk < 16; ++kk) {
      float4 a = *(const float4*)&As[kk][ty << 2];
      float4 b = *(const float4*)&Bs[kk][tx << 2];
      float af[4] = {a.x, a.y, a.z, a.w};
      float bf[4] = {b.x, b.y, b.z, b.w};
      #pragma unroll
      for (int i = 0; i < 4; ++i)
        #pragma unroll
        for (int j = 0; j < 4; ++j)
          acc[i][j] = fmaf(af[i], bf[j], acc[i][j]);
    }
    __syncthreads();
  }
  float* Cp = C + (size_t)(by * 64 + (ty << 2)) * N + bx * 64 + (tx << 2);
  #pragma unroll
  for (int i = 0; i < 4; ++i) {
    float4 o = make_float4(acc[i][0], acc[i][1], acc[i][2], acc[i][3]);
    *(float4*)(Cp + (size_t)i * N) = o;
  }
}

__global__ __launch_bounds__(256) void k_gemm_tn(const float* __restrict__ Y,
                                                 const float* __restrict__ F,
                                                 float* __restrict__ C,
                                                 int Kc, int Dd, int chunk) {
  __shared__ float As[16][68];
  __shared__ float Bs[16][68];
  const int tid = threadIdx.x;
  const int tx = tid & 15, ty = tid >> 4;
  const int bx = blockIdx.x, by = blockIdx.y, bz = blockIdx.z;
  const int lr = tid >> 4, lc4 = (tid & 15) << 2;
  float acc[4][4] = {};
  const int b0 = bz * chunk;
  for (int bb = b0; bb < b0 + chunk; bb += 16) {
    *(float4*)&As[lr][lc4] = *(const float4*)(Y + (size_t)(bb + lr) * Kc + by * 64 + lc4);
    *(float4*)&Bs[lr][lc4] = *(const float4*)(F + (size_t)(bb + lr) * Dd + bx * 64 + lc4);
    __syncthreads();
    #pragma unroll
    for (int kk = 0; kk < 16; ++kk) {
      float4 a = *(const float4*)&As[kk][ty << 2];
      float4 b = *(const float4*)&Bs[kk][tx << 2];
      float af[4] = {a.x, a.y, a.z, a.w};
      float bf[4] = {b.x, b.y, b.z, b.w};
      #pragma unroll
      for (int i = 0; i < 4; ++i)
        #pragma unroll
        for (int j = 0; j < 4; ++j)
          acc[i][j] = fmaf(af[i], bf[j], acc[i][j]);
    }
    __syncthreads();
  }
  #pragma unroll
  for (int i = 0; i < 4; ++i)
    #pragma unroll
    for (int j = 0; j < 4; ++j)
      atomicAdd(&C[(size_t)(by * 64 + (ty << 2) + i) * Dd + bx * 64 + (tx << 2) + j],
                acc[i][j]);
}

__global__ __launch_bounds__(256) void k_colsum(const float* __restrict__ Y,
                                                float* __restrict__ norm,
                                                int Bb, int Kc) {
  int k = blockIdx.x * 256 + threadIdx.x;
  int chunk = Bb / gridDim.y;
  int b0 = blockIdx.y * chunk;
  float s = 0.0f;
  for (int b = b0; b < b0 + chunk; ++b) s += Y[(size_t)b * Kc + k];
  atomicAdd(&norm[k], s);
}

__global__ __launch_bounds__(256) void k_gumbel(float* __restrict__ Y,
                                                const float* __restrict__ Ua,
                                                const float* __restrict__ Ub,
                                                float* __restrict__ assign_out,
                                                int Kc) {
  __shared__ float sb[256];
  __shared__ float svals[256];
  __shared__ int sidx[256];
  int row = blockIdx.x, tid = threadIdx.x;
  float* ya = Y + (size_t)row * Kc;
  float l[4], s[4];
  float lm = -3.4e38f;
  #pragma unroll
  for (int j = 0; j < 4; ++j) {
    int k = j * 256 + tid;
    l[j] = ya[k];
    float u = Ua[(size_t)row * Kc + k];
    u = u * (1.0f - 2e-6f) + 1e-6f;
    float g = -__logf(-__logf(u));
    s[j] = (l[j] + g) * 2.0f;
    lm = fmaxf(lm, s[j]);
  }
  float m = bmax(lm, sb);
  float e[4]; float sum = 0.0f;
  #pragma unroll
  for (int j = 0; j < 4; ++j) { e[j] = __expf(s[j] - m); sum += e[j]; }
  sum = bsum(sum, sb);
  #pragma unroll
  for (int j = 0; j < 4; ++j) ya[j * 256 + tid] = e[j] / sum;

  if (Ub != nullptr) {
    float bv = -3.4e38f; int bi = 0x7fffffff;
    #pragma unroll
    for (int j = 0; j < 4; ++j) {
      int k = j * 256 + tid;
      float u = Ub[(size_t)row * Kc + k];
      u = u * (1.0f - 2e-6f) + 1e-6f;
      float g = -__logf(-__logf(u));
      float t = l[j] + g;
      if (t > bv || (t == bv && k < bi)) { bv = t; bi = k; }
    }
    svals[tid] = bv; sidx[tid] = bi; __syncthreads();
    for (int st = 128; st > 0; st >>= 1) {
      if (tid < st) {
        if (svals[tid + st] > svals[tid] ||
            (svals[tid + st] == svals[tid] && sidx[tid + st] < sidx[tid])) {
          svals[tid] = svals[tid + st]; sidx[tid] = sidx[tid + st];
        }
      }
      __syncthreads();
    }
    if (tid == 0) assign_out[row] = (float)sidx[0];
  }
}

// ======================= persistent-column bf16-MFMA LSE (8-wave) =======================
// sumexp[row] += sum_cols exp(dot(A[row],B[col])/TEMP).
// Grid (8 chunks == XCDs, M/128); 512 threads = 8 waves (2x4 wave grid) so each
// SIMD holds 2 waves -> ds_read/staging stalls of one wave overlap MFMA of the other.
// A fragments hoisted to registers (a[4][8]); B tiles (128 cols x 256 K bf16)
// double-buffered in LDS (2 x 64 KB), staged via global_load_lds with the
// both-sides XOR slot swizzle. Exp-sums in registers; 4 atomics/row/block at end.
#define LSE_TILE_SHORTS 32768  // 128 cols * 256 K

__device__ __forceinline__ void lse_stage512(const short* __restrict__ Bm,
                                             short* dst, int colb, int tid) {
  const int rbase = tid >> 5;   // dest row = p*16 + rbase (512 B rows)
  const int sl = tid & 31;      // dest 16B slot within row
  #pragma unroll
  for (int p = 0; p < 8; ++p) {
    const int r = p * 16 + rbase;
    const int ss = sl ^ (r & 7);  // inverse-swizzled source slot
    const short* g = Bm + (size_t)(colb + r) * 256 + ss * 8;
    __builtin_amdgcn_global_load_lds(
        (const __attribute__((address_space(1))) unsigned int*)g,
        (__attribute__((address_space(3))) unsigned int*)(dst + p * 4096 + tid * 8),
        16, 0, 0);
  }
}

__global__ __launch_bounds__(512, 2) void k_lse2(const short* __restrict__ A,
                                                 const short* __restrict__ Bm,
                                                 float* __restrict__ sumexp,
                                                 int colsPerChunk) {
  __shared__ short lds[2 * LSE_TILE_SHORTS];  // 128 KB
  const int tid = threadIdx.x;
  const int lane = tid & 63, wv = tid >> 6;
  const int wr = wv >> 2, wc = wv & 3;        // 2x4 wave grid: 64 rows x 32 cols each
  const int row0 = blockIdx.y * 128;
  const int col0 = blockIdx.x * colsPerChunk;
  const int ntiles = colsPerChunk >> 7;
  const int g = lane >> 4;

  // hoist A fragments: rows wr*64 + m*16 + (lane&15); k-step k covers K [k*32,(k+1)*32)
  short8_t a[4][8];
  #pragma unroll
  for (int m = 0; m < 4; ++m) {
    const size_t rbase = (size_t)(row0 + wr * 64 + m * 16 + (lane & 15)) * 256;
    #pragma unroll
    for (int k = 0; k < 8; ++k)
      a[m][k] = *(const short8_t*)&A[rbase + k * 32 + g * 8];
  }

  float rsum[4][4];
  #pragma unroll
  for (int m = 0; m < 4; ++m)
    #pragma unroll
    for (int r = 0; r < 4; ++r) rsum[m][r] = 0.0f;

  lse_stage512(Bm, lds, col0, tid);
  __syncthreads();

  const float invT = 1.0f / 0.07f;
  int cur = 0;
  for (int t = 0; t < ntiles; ++t) {
    if (t + 1 < ntiles)
      lse_stage512(Bm, lds + (cur ^ 1) * LSE_TILE_SHORTS, col0 + (t + 1) * 128, tid);

    const short* Bt = lds + cur * LSE_TILE_SHORTS;
    f32x4_t acc[4][2];
    #pragma unroll
    for (int m = 0; m < 4; ++m)
      #pragma unroll
      for (int n = 0; n < 2; ++n)
        acc[m][n] = (f32x4_t){0.f, 0.f, 0.f, 0.f};

    #pragma unroll
    for (int k = 0; k < 8; ++k) {
      short8_t bf[2];
      #pragma unroll
      for (int n = 0; n < 2; ++n) {
        const int r = wc * 32 + n * 16 + (lane & 15);
        bf[n] = *(const short8_t*)&Bt[r * 256 + (((k * 4 + g) ^ (r & 7)) * 8)];
      }
      #pragma unroll
      for (int m = 0; m < 4; ++m)
        #pragma unroll
        for (int n = 0; n < 2; ++n)
          acc[m][n] = __builtin_amdgcn_mfma_f32_16x16x32_bf16(a[m][k], bf[n], acc[m][n], 0, 0, 0);
    }

    // per-tile epilogue: exp and accumulate into register row-sums
    #pragma unroll
    for (int m = 0; m < 4; ++m)
      #pragma unroll
      for (int r = 0; r < 4; ++r)
        rsum[m][r] += __expf(acc[m][0][r] * invT) + __expf(acc[m][1][r] * invT);

    __syncthreads();
    cur ^= 1;
  }

  // final: reduce over the 16 lanes of each group, one atomic per row per wave
  #pragma unroll
  for (int m = 0; m < 4; ++m)
    #pragma unroll
    for (int r = 0; r < 4; ++r) {
      float v = rsum[m][r];
      v += __shfl_xor(v, 1);
      v += __shfl_xor(v, 2);
      v += __shfl_xor(v, 4);
      v += __shfl_xor(v, 8);
      if ((lane & 15) == 0)
        atomicAdd(&sumexp[row0 + wr * 64 + m * 16 + g * 4 + r], v);
    }
}

__global__ __launch_bounds__(256) void k_loss(const float* __restrict__ lpn,
                                              const float* __restrict__ sen, int nb,
                                              const float* __restrict__ lpk,
                                              const float* __restrict__ sek, int nk,
                                              float* __restrict__ out) {
  __shared__ float sb[256];
  int tid = threadIdx.x;
  const float invT = 1.0f / 0.07f;
  float s = 0.0f;
  for (int b = tid; b < nb; b += 256) {
    float lp = lpn[b] * invT;
    s += logf(expf(lp) + sen[b]) - lp;
  }
  float s1 = bsum(s, sb);
  s = 0.0f;
  for (int b = tid; b < nk; b += 256) {
    float lp = lpk[b] * invT;
    s += logf(expf(lp) + sek[b]) - lp;
  }
  float s2 = bsum(s, sb);
  if (tid == 0) out[0] = s1 / (float)nb + s2 / (float)nk;
}

extern "C" void kernel_launch(void* const* d_in, const int* in_sizes, int n_in,
                              void* d_out, int out_size, void* d_ws, size_t ws_size,
                              hipStream_t stream) {
  const float* x1     = (const float*)d_in[0];
  const float* x2     = (const float*)d_in[1];
  const float* W1     = (const float*)d_in[2];
  const float* W2     = (const float*)d_in[3];
  const float* c1     = (const float*)d_in[4];
  const float* c2     = (const float*)d_in[5];
  const float* qn     = (const float*)d_in[6];
  const float* qk     = (const float*)d_in[7];
  const float* u1a    = (const float*)d_in[8];
  const float* u1b    = (const float*)d_in[9];
  const float* u2a    = (const float*)d_in[10];
  const float* qnoise = (const float*)d_in[12];

  float* out_assign = (float*)d_out;
  float* out_feat2  = out_assign + B_N;
  float* out_aggk2  = out_feat2 + (size_t)B_N * D_D;
  float* out_loss   = out_aggk2 + (size_t)K_C * D_D;

  float* w = (float*)d_ws;
  float* f1     = w; w += (size_t)B_N * D_D;
  __hip_bfloat16* f1b    = (__hip_bfloat16*)w; w += (size_t)B_N * D_D / 2;
  float* ctx1n  = w; w += (size_t)K_C * D_D;
  float* ctx2n  = w; w += (size_t)K_C * D_D;
  __hip_bfloat16* qnnb   = (__hip_bfloat16*)w; w += (size_t)L_Q * D_D / 2;
  float* qkn    = w; w += (size_t)KQ_ * D_D;
  __hip_bfloat16* qcombb = (__hip_bfloat16*)w; w += (size_t)KQ_ * D_D / 2;
  float* ybuf   = w; w += (size_t)B_N * K_C;
  float* aggk1  = w; w += (size_t)K_C * D_D;
  __hip_bfloat16* aggk1b = (__hip_bfloat16*)w; w += (size_t)K_C * D_D / 2;
  float* zero0 = w;
  float* aggt1  = w; w += (size_t)K_C * D_D;
  float* aggt2  = w; w += (size_t)K_C * D_D;
  float* norm1  = w; w += K_C;
  float* norm2  = w; w += K_C;
  float* sen    = w; w += B_N;
  float* sek    = w; w += K_C;
  float* zend   = w;
  float* lpn    = w; w += B_N;
  float* lpk    = w; w += K_C;
  hipMemsetAsync(zero0, 0, (size_t)(zend - zero0) * sizeof(float), stream);

  k_gemm_nn<<<dim3(D_D / 64, B_N / 64), 256, 0, stream>>>(x1, W1, f1, B_N, D_D, D_IN);
  k_rownorm_dual<<<B_N, 256, 0, stream>>>(f1, f1, f1b);
  k_gemm_nn<<<dim3(D_D / 64, B_N / 64), 256, 0, stream>>>(x2, W2, out_feat2, B_N, D_D, D_IN);
  k_rownorm<<<B_N, 256, 0, stream>>>(out_feat2, out_feat2);

  k_rownorm<<<K_C, 256, 0, stream>>>(c1, ctx1n);
  k_rownorm<<<K_C, 256, 0, stream>>>(c2, ctx2n);
  k_rownorm_bf16<<<L_Q, 256, 0, stream>>>(qn, qnnb);
  k_rownorm<<<KQ_, 256, 0, stream>>>(qk, qkn);
  k_rownorm_comb_bf16<<<KQ_, 256, 0, stream>>>(qkn, qnoise, qcombb);

  k_gemm_nt<<<dim3(K_C / 64, B_N / 64), 256, 0, stream>>>(f1, ctx1n, ybuf, B_N, K_C, D_D);
  k_gumbel<<<B_N, 256, 0, stream>>>(ybuf, u1a, u1b, out_assign, K_C);
  k_colsum<<<dim3(K_C / 256, 16), 256, 0, stream>>>(ybuf, norm1, B_N, K_C);
  k_gemm_tn<<<dim3(D_D / 64, K_C / 64, 8), 256, 0, stream>>>(ybuf, f1, aggt1, K_C, D_D, B_N / 8);
  k_rownorm_div_dual<<<K_C, 256, 0, stream>>>(aggt1, norm1, aggk1, aggk1b);

  k_gemm_nt<<<dim3(K_C / 64, B_N / 64), 256, 0, stream>>>(out_feat2, ctx2n, ybuf, B_N, K_C, D_D);
  k_gumbel<<<B_N, 256, 0, stream>>>(ybuf, u2a, nullptr, nullptr, K_C);
  k_colsum<<<dim3(K_C / 256, 16), 256, 0, stream>>>(ybuf, norm2, B_N, K_C);
  k_gemm_tn<<<dim3(D_D / 64, K_C / 64, 8), 256, 0, stream>>>(ybuf, out_feat2, aggt2, K_C, D_D, B_N / 8);
  k_rownorm_div<<<K_C, 256, 0, stream>>>(aggt2, norm2, out_aggk2);

  k_dotrows<<<B_N, 256, 0, stream>>>(f1, out_feat2, lpn);
  k_dotrows<<<K_C, 256, 0, stream>>>(aggk1, out_aggk2, lpk);

  // persistent-column LSE: grid (8 chunks == XCDs, rows/128), 512 threads
  k_lse2<<<dim3(8, B_N / 128), 512, 0, stream>>>((const short*)f1b, (const short*)qnnb, sen, L_Q / 8);
  k_lse2<<<dim3(8, K_C / 128), 512, 0, stream>>>((const short*)aggk1b, (const short*)qcombb, sek, KQ_ / 8);

  k_loss<<<1, 256, 0, stream>>>(lpn, sen, B_N, lpk, sek, K_C, out_loss);
}

// Round 7
// 632.900 us; speedup vs baseline: 2.4462x; 1.2033x over previous
//
#include <hip/hip_runtime.h>
#include <hip/hip_bf16.h>
#include <math.h>

#define B_N  4096
#define D_IN 1024
#define D_D  256
#define K_C  1024
#define L_Q  32768
#define KQ_  4096

typedef __attribute__((ext_vector_type(8))) short short8_t;
typedef __attribute__((ext_vector_type(4))) float f32x4_t;

__device__ __forceinline__ float bsum(float v, float* sb) {
  int t = threadIdx.x;
  sb[t] = v; __syncthreads();
  #pragma unroll
  for (int s = 128; s > 0; s >>= 1) {
    if (t < s) sb[t] += sb[t + s];
    __syncthreads();
  }
  float r = sb[0]; __syncthreads();
  return r;
}

__device__ __forceinline__ float bmax(float v, float* sb) {
  int t = threadIdx.x;
  sb[t] = v; __syncthreads();
  #pragma unroll
  for (int s = 128; s > 0; s >>= 1) {
    if (t < s) sb[t] = fmaxf(sb[t], sb[t + s]);
    __syncthreads();
  }
  float r = sb[0]; __syncthreads();
  return r;
}

__global__ __launch_bounds__(256) void k_rownorm(const float* __restrict__ src,
                                                 float* __restrict__ dst) {
  __shared__ float sb[256];
  int row = blockIdx.x, tid = threadIdx.x;
  float v = src[(size_t)row * 256 + tid];
  float ss = bsum(v * v, sb);
  dst[(size_t)row * 256 + tid] = v * rsqrtf(fmaxf(ss, 1e-12f));
}

__global__ __launch_bounds__(256) void k_rownorm_bf16(const float* __restrict__ src,
                                                      __hip_bfloat16* __restrict__ dst) {
  __shared__ float sb[256];
  int row = blockIdx.x, tid = threadIdx.x;
  float v = src[(size_t)row * 256 + tid];
  float ss = bsum(v * v, sb);
  dst[(size_t)row * 256 + tid] = __float2bfloat16(v * rsqrtf(fmaxf(ss, 1e-12f)));
}

// sum 4 partial-K slabs, l2norm, write fp32 + bf16
__global__ __launch_bounds__(256) void k_rownorm_sum4_dual(const float* __restrict__ part,
                                                           float* __restrict__ dstf,
                                                           __hip_bfloat16* __restrict__ dstb) {
  __shared__ float sb[256];
  int row = blockIdx.x, tid = threadIdx.x;
  size_t i = (size_t)row * 256 + tid;
  const size_t S = (size_t)B_N * 256;
  float v = (part[i] + part[i + S]) + (part[i + 2 * S] + part[i + 3 * S]);
  float ss = bsum(v * v, sb);
  float o = v * rsqrtf(fmaxf(ss, 1e-12f));
  dstf[i] = o;
  dstb[i] = __float2bfloat16(o);
}

// sum 4 partial-K slabs, l2norm, write fp32 only
__global__ __launch_bounds__(256) void k_rownorm_sum4(const float* __restrict__ part,
                                                      float* __restrict__ dstf) {
  __shared__ float sb[256];
  int row = blockIdx.x, tid = threadIdx.x;
  size_t i = (size_t)row * 256 + tid;
  const size_t S = (size_t)B_N * 256;
  float v = (part[i] + part[i + S]) + (part[i + 2 * S] + part[i + 3 * S]);
  float ss = bsum(v * v, sb);
  dstf[i] = v * rsqrtf(fmaxf(ss, 1e-12f));
}

__global__ __launch_bounds__(256) void k_rownorm_comb_bf16(const float* __restrict__ a,
                                                           const float* __restrict__ b,
                                                           __hip_bfloat16* __restrict__ dst) {
  __shared__ float sb[256];
  int row = blockIdx.x, tid = threadIdx.x;
  size_t i = (size_t)row * 256 + tid;
  float v = 2.0f * a[i] + b[i];
  float ss = bsum(v * v, sb);
  dst[i] = __float2bfloat16(v * rsqrtf(fmaxf(ss, 1e-12f)));
}

__global__ __launch_bounds__(256) void k_rownorm_div(const float* __restrict__ src,
                                                     const float* __restrict__ norm,
                                                     float* __restrict__ dst) {
  __shared__ float sb[256];
  int row = blockIdx.x, tid = threadIdx.x;
  size_t i = (size_t)row * 256 + tid;
  float v = src[i] / (norm[row] + 1e-8f);
  float ss = bsum(v * v, sb);
  dst[i] = v * rsqrtf(fmaxf(ss, 1e-12f));
}

__global__ __launch_bounds__(256) void k_rownorm_div_dual(const float* __restrict__ src,
                                                          const float* __restrict__ norm,
                                                          float* __restrict__ dstf,
                                                          __hip_bfloat16* __restrict__ dstb) {
  __shared__ float sb[256];
  int row = blockIdx.x, tid = threadIdx.x;
  size_t i = (size_t)row * 256 + tid;
  float v = src[i] / (norm[row] + 1e-8f);
  float ss = bsum(v * v, sb);
  float o = v * rsqrtf(fmaxf(ss, 1e-12f));
  dstf[i] = o;
  dstb[i] = __float2bfloat16(o);
}

__global__ __launch_bounds__(256) void k_dotrows(const float* __restrict__ a,
                                                 const float* __restrict__ b,
                                                 float* __restrict__ out) {
  __shared__ float sb[256];
  int row = blockIdx.x, tid = threadIdx.x;
  size_t i = (size_t)row * 256 + tid;
  float s = bsum(a[i] * b[i], sb);
  if (tid == 0) out[row] = s;
}

// split-K GEMM NN partials: Cpart[z][M][N] = A[M, z-chunk] @ B[z-chunk, N]
__global__ __launch_bounds__(256) void k_gemm_nn_part(const float* __restrict__ A,
                                                      const float* __restrict__ Bm,
                                                      float* __restrict__ Cpart,
                                                      int M, int N, int K, int kchunk) {
  __shared__ float As[16][68];
  __shared__ float Bs[16][68];
  const int tid = threadIdx.x;
  const int tx = tid & 15, ty = tid >> 4;
  const int bx = blockIdx.x, by = blockIdx.y, bz = blockIdx.z;
  const int ar = tid >> 2, ac4 = (tid & 3) << 2;
  const int br = tid >> 4, bc4 = (tid & 15) << 2;
  float acc[4][4] = {};
  const float* Ap = A + (size_t)(by * 64 + ar) * K + ac4;
  const float* Bp = Bm + (size_t)br * N + bx * 64 + bc4;
  const int k0beg = bz * kchunk, k0end = k0beg + kchunk;
  for (int k0 = k0beg; k0 < k0end; k0 += 16) {
    float4 av = *(const float4*)(Ap + k0);
    As[ac4 + 0][ar] = av.x; As[ac4 + 1][ar] = av.y;
    As[ac4 + 2][ar] = av.z; As[ac4 + 3][ar] = av.w;
    *(float4*)&Bs[br][bc4] = *(const float4*)(Bp + (size_t)k0 * N);
    __syncthreads();
    #pragma unroll
    for (int kk = 0; kk < 16; ++kk) {
      float4 a = *(const float4*)&As[kk][ty << 2];
      float4 b = *(const float4*)&Bs[kk][tx << 2];
      float af[4] = {a.x, a.y, a.z, a.w};
      float bf[4] = {b.x, b.y, b.z, b.w};
      #pragma unroll
      for (int i = 0; i < 4; ++i)
        #pragma unroll
        for (int j = 0; j < 4; ++j)
          acc[i][j] = fmaf(af[i], bf[j], acc[i][j]);
    }
    __syncthreads();
  }
  float* Cp = Cpart + (size_t)bz * M * N +
              (size_t)(by * 64 + (ty << 2)) * N + bx * 64 + (tx << 2);
  #pragma unroll
  for (int i = 0; i < 4; ++i) {
    float4 o = make_float4(acc[i][0], acc[i][1], acc[i][2], acc[i][3]);
    *(float4*)(Cp + (size_t)i * N) = o;
  }
}

__global__ __launch_bounds__(256) void k_gemm_nt(const float* __restrict__ A,
                                                 const float* __restrict__ Bm,
                                                 float* __restrict__ C,
                                                 int M, int N, int K) {
  __shared__ float As[16][68];
  __shared__ float Bs[16][68];
  const int tid = threadIdx.x;
  const int tx = tid & 15, ty = tid >> 4;
  const int bx = blockIdx.x, by = blockIdx.y;
  const int lr = tid >> 2, lc4 = (tid & 3) << 2;
  float acc[4][4] = {};
  const float* Ap = A + (size_t)(by * 64 + lr) * K + lc4;
  const float* Bp = Bm + (size_t)(bx * 64 + lr) * K + lc4;
  for (int k0 = 0; k0 < K; k0 += 16) {
    float4 av = *(const float4*)(Ap + k0);
    As[lc4 + 0][lr] = av.x; As[lc4 + 1][lr] = av.y;
    As[lc4 + 2][lr] = av.z; As[lc4 + 3][lr] = av.w;
    float4 bv = *(const float4*)(Bp + k0);
    Bs[lc4 + 0][lr] = bv.x; Bs[lc4 + 1][lr] = bv.y;
    Bs[lc4 + 2][lr] = bv.z; Bs[lc4 + 3][lr] = bv.w;
    __syncthreads();
    #pragma unroll
    for (int kk = 0; kk < 16; ++kk) {
      float4 a = *(const float4*)&As[kk][ty << 2];
      float4 b = *(const float4*)&Bs[kk][tx << 2];
      float af[4] = {a.x, a.y, a.z, a.w};
      float bf[4] = {b.x, b.y, b.z, b.w};
      #pragma unroll
      for (int i = 0; i < 4; ++i)
        #pragma unroll
        for (int j = 0; j < 4; ++j)
          acc[i][j] = fmaf(af[i], bf[j], acc[i][j]);
    }
    __syncthreads();
  }
  float* Cp = C + (size_t)(by * 64 + (ty << 2)) * N + bx * 64 + (tx << 2);
  #pragma unroll
  for (int i = 0; i < 4; ++i) {
    float4 o = make_float4(acc[i][0], acc[i][1], acc[i][2], acc[i][3]);
    *(float4*)(Cp + (size_t)i * N) = o;
  }
}

__global__ __launch_bounds__(256) void k_gemm_tn(const float* __restrict__ Y,
                                                 const float* __restrict__ F,
                                                 float* __restrict__ C,
                                                 int Kc, int Dd, int chunk) {
  __shared__ float As[16][68];
  __shared__ float Bs[16][68];
  const int tid = threadIdx.x;
  const int tx = tid & 15, ty = tid >> 4;
  const int bx = blockIdx.x, by = blockIdx.y, bz = blockIdx.z;
  const int lr = tid >> 4, lc4 = (tid & 15) << 2;
  float acc[4][4] = {};
  const int b0 = bz * chunk;
  for (int bb = b0; bb < b0 + chunk; bb += 16) {
    *(float4*)&As[lr][lc4] = *(const float4*)(Y + (size_t)(bb + lr) * Kc + by * 64 + lc4);
    *(float4*)&Bs[lr][lc4] = *(const float4*)(F + (size_t)(bb + lr) * Dd + bx * 64 + lc4);
    __syncthreads();
    #pragma unroll
    for (int kk = 0; kk < 16; ++kk) {
      float4 a = *(const float4*)&As[kk][ty << 2];
      float4 b = *(const float4*)&Bs[kk][tx << 2];
      float af[4] = {a.x, a.y, a.z, a.w};
      float bf[4] = {b.x, b.y, b.z, b.w};
      #pragma unroll
      for (int i = 0; i < 4; ++i)
        #pragma unroll
        for (int j = 0; j < 4; ++j)
          acc[i][j] = fmaf(af[i], bf[j], acc[i][j]);
    }
    __syncthreads();
  }
  #pragma unroll
  for (int i = 0; i < 4; ++i)
    #pragma unroll
    for (int j = 0; j < 4; ++j)
      atomicAdd(&C[(size_t)(by * 64 + (ty << 2) + i) * Dd + bx * 64 + (tx << 2) + j],
                acc[i][j]);
}

__global__ __launch_bounds__(256) void k_colsum(const float* __restrict__ Y,
                                                float* __restrict__ norm,
                                                int Bb, int Kc) {
  int k = blockIdx.x * 256 + threadIdx.x;
  int chunk = Bb / gridDim.y;
  int b0 = blockIdx.y * chunk;
  float s = 0.0f;
  for (int b = b0; b < b0 + chunk; ++b) s += Y[(size_t)b * Kc + k];
  atomicAdd(&norm[k], s);
}

__global__ __launch_bounds__(256) void k_gumbel(float* __restrict__ Y,
                                                const float* __restrict__ Ua,
                                                const float* __restrict__ Ub,
                                                float* __restrict__ assign_out,
                                                int Kc) {
  __shared__ float sb[256];
  __shared__ float svals[256];
  __shared__ int sidx[256];
  int row = blockIdx.x, tid = threadIdx.x;
  float* ya = Y + (size_t)row * Kc;
  float l[4], s[4];
  float lm = -3.4e38f;
  #pragma unroll
  for (int j = 0; j < 4; ++j) {
    int k = j * 256 + tid;
    l[j] = ya[k];
    float u = Ua[(size_t)row * Kc + k];
    u = u * (1.0f - 2e-6f) + 1e-6f;
    float g = -__logf(-__logf(u));
    s[j] = (l[j] + g) * 2.0f;
    lm = fmaxf(lm, s[j]);
  }
  float m = bmax(lm, sb);
  float e[4]; float sum = 0.0f;
  #pragma unroll
  for (int j = 0; j < 4; ++j) { e[j] = __expf(s[j] - m); sum += e[j]; }
  sum = bsum(sum, sb);
  #pragma unroll
  for (int j = 0; j < 4; ++j) ya[j * 256 + tid] = e[j] / sum;

  if (Ub != nullptr) {
    float bv = -3.4e38f; int bi = 0x7fffffff;
    #pragma unroll
    for (int j = 0; j < 4; ++j) {
      int k = j * 256 + tid;
      float u = Ub[(size_t)row * Kc + k];
      u = u * (1.0f - 2e-6f) + 1e-6f;
      float g = -__logf(-__logf(u));
      float t = l[j] + g;
      if (t > bv || (t == bv && k < bi)) { bv = t; bi = k; }
    }
    svals[tid] = bv; sidx[tid] = bi; __syncthreads();
    for (int st = 128; st > 0; st >>= 1) {
      if (tid < st) {
        if (svals[tid + st] > svals[tid] ||
            (svals[tid + st] == svals[tid] && sidx[tid + st] < sidx[tid])) {
          svals[tid] = svals[tid + st]; sidx[tid] = sidx[tid + st];
        }
      }
      __syncthreads();
    }
    if (tid == 0) assign_out[row] = (float)sidx[0];
  }
}

// ======================= persistent-column bf16-MFMA LSE (8-wave) =======================
#define LSE_TILE_SHORTS 32768  // 128 cols * 256 K

__device__ __forceinline__ void lse_stage512(const short* __restrict__ Bm,
                                             short* dst, int colb, int tid) {
  const int rbase = tid >> 5;
  const int sl = tid & 31;
  #pragma unroll
  for (int p = 0; p < 8; ++p) {
    const int r = p * 16 + rbase;
    const int ss = sl ^ (r & 7);
    const short* g = Bm + (size_t)(colb + r) * 256 + ss * 8;
    __builtin_amdgcn_global_load_lds(
        (const __attribute__((address_space(1))) unsigned int*)g,
        (__attribute__((address_space(3))) unsigned int*)(dst + p * 4096 + tid * 8),
        16, 0, 0);
  }
}

__global__ __launch_bounds__(512, 2) void k_lse2(const short* __restrict__ A,
                                                 const short* __restrict__ Bm,
                                                 float* __restrict__ sumexp,
                                                 int colsPerChunk) {
  __shared__ short lds[2 * LSE_TILE_SHORTS];  // 128 KB
  const int tid = threadIdx.x;
  const int lane = tid & 63, wv = tid >> 6;
  const int wr = wv >> 2, wc = wv & 3;
  const int row0 = blockIdx.y * 128;
  const int col0 = blockIdx.x * colsPerChunk;
  const int ntiles = colsPerChunk >> 7;
  const int g = lane >> 4;

  short8_t a[4][8];
  #pragma unroll
  for (int m = 0; m < 4; ++m) {
    const size_t rbase = (size_t)(row0 + wr * 64 + m * 16 + (lane & 15)) * 256;
    #pragma unroll
    for (int k = 0; k < 8; ++k)
      a[m][k] = *(const short8_t*)&A[rbase + k * 32 + g * 8];
  }

  float rsum[4][4];
  #pragma unroll
  for (int m = 0; m < 4; ++m)
    #pragma unroll
    for (int r = 0; r < 4; ++r) rsum[m][r] = 0.0f;

  lse_stage512(Bm, lds, col0, tid);
  __syncthreads();

  const float invT = 1.0f / 0.07f;
  int cur = 0;
  for (int t = 0; t < ntiles; ++t) {
    if (t + 1 < ntiles)
      lse_stage512(Bm, lds + (cur ^ 1) * LSE_TILE_SHORTS, col0 + (t + 1) * 128, tid);

    const short* Bt = lds + cur * LSE_TILE_SHORTS;
    f32x4_t acc[4][2];
    #pragma unroll
    for (int m = 0; m < 4; ++m)
      #pragma unroll
      for (int n = 0; n < 2; ++n)
        acc[m][n] = (f32x4_t){0.f, 0.f, 0.f, 0.f};

    #pragma unroll
    for (int k = 0; k < 8; ++k) {
      short8_t bf[2];
      #pragma unroll
      for (int n = 0; n < 2; ++n) {
        const int r = wc * 32 + n * 16 + (lane & 15);
        bf[n] = *(const short8_t*)&Bt[r * 256 + (((k * 4 + g) ^ (r & 7)) * 8)];
      }
      #pragma unroll
      for (int m = 0; m < 4; ++m)
        #pragma unroll
        for (int n = 0; n < 2; ++n)
          acc[m][n] = __builtin_amdgcn_mfma_f32_16x16x32_bf16(a[m][k], bf[n], acc[m][n], 0, 0, 0);
    }

    #pragma unroll
    for (int m = 0; m < 4; ++m)
      #pragma unroll
      for (int r = 0; r < 4; ++r)
        rsum[m][r] += __expf(acc[m][0][r] * invT) + __expf(acc[m][1][r] * invT);

    __syncthreads();
    cur ^= 1;
  }

  #pragma unroll
  for (int m = 0; m < 4; ++m)
    #pragma unroll
    for (int r = 0; r < 4; ++r) {
      float v = rsum[m][r];
      v += __shfl_xor(v, 1);
      v += __shfl_xor(v, 2);
      v += __shfl_xor(v, 4);
      v += __shfl_xor(v, 8);
      if ((lane & 15) == 0)
        atomicAdd(&sumexp[row0 + wr * 64 + m * 16 + g * 4 + r], v);
    }
}

__global__ __launch_bounds__(256) void k_loss(const float* __restrict__ lpn,
                                              const float* __restrict__ sen, int nb,
                                              const float* __restrict__ lpk,
                                              const float* __restrict__ sek, int nk,
                                              float* __restrict__ out) {
  __shared__ float sb[256];
  int tid = threadIdx.x;
  const float invT = 1.0f / 0.07f;
  float s = 0.0f;
  for (int b = tid; b < nb; b += 256) {
    float lp = lpn[b] * invT;
    s += logf(expf(lp) + sen[b]) - lp;
  }
  float s1 = bsum(s, sb);
  s = 0.0f;
  for (int b = tid; b < nk; b += 256) {
    float lp = lpk[b] * invT;
    s += logf(expf(lp) + sek[b]) - lp;
  }
  float s2 = bsum(s, sb);
  if (tid == 0) out[0] = s1 / (float)nb + s2 / (float)nk;
}

extern "C" void kernel_launch(void* const* d_in, const int* in_sizes, int n_in,
                              void* d_out, int out_size, void* d_ws, size_t ws_size,
                              hipStream_t stream) {
  const float* x1     = (const float*)d_in[0];
  const float* x2     = (const float*)d_in[1];
  const float* W1     = (const float*)d_in[2];
  const float* W2     = (const float*)d_in[3];
  const float* c1     = (const float*)d_in[4];
  const float* c2     = (const float*)d_in[5];
  const float* qn     = (const float*)d_in[6];
  const float* qk     = (const float*)d_in[7];
  const float* u1a    = (const float*)d_in[8];
  const float* u1b    = (const float*)d_in[9];
  const float* u2a    = (const float*)d_in[10];
  const float* qnoise = (const float*)d_in[12];

  float* out_assign = (float*)d_out;
  float* out_feat2  = out_assign + B_N;
  float* out_aggk2  = out_feat2 + (size_t)B_N * D_D;
  float* out_loss   = out_aggk2 + (size_t)K_C * D_D;

  float* w = (float*)d_ws;
  float* f1     = w; w += (size_t)B_N * D_D;
  __hip_bfloat16* f1b    = (__hip_bfloat16*)w; w += (size_t)B_N * D_D / 2;
  float* ctx1n  = w; w += (size_t)K_C * D_D;
  float* ctx2n  = w; w += (size_t)K_C * D_D;
  __hip_bfloat16* qnnb   = (__hip_bfloat16*)w; w += (size_t)L_Q * D_D / 2;
  float* qkn    = w; w += (size_t)KQ_ * D_D;
  __hip_bfloat16* qcombb = (__hip_bfloat16*)w; w += (size_t)KQ_ * D_D / 2;
  float* ybuf   = w; w += (size_t)B_N * K_C;
  float* aggk1  = w; w += (size_t)K_C * D_D;
  __hip_bfloat16* aggk1b = (__hip_bfloat16*)w; w += (size_t)K_C * D_D / 2;
  float* fpart  = w; w += (size_t)4 * B_N * D_D;   // 16 MB split-K partials
  float* zero0 = w;
  float* aggt1  = w; w += (size_t)K_C * D_D;
  float* aggt2  = w; w += (size_t)K_C * D_D;
  float* norm1  = w; w += K_C;
  float* norm2  = w; w += K_C;
  float* sen    = w; w += B_N;
  float* sek    = w; w += K_C;
  float* zend   = w;
  float* lpn    = w; w += B_N;
  float* lpk    = w; w += K_C;
  hipMemsetAsync(zero0, 0, (size_t)(zend - zero0) * sizeof(float), stream);

  // features: split-K=4 partial slabs (deterministic), fused sum+l2norm
  k_gemm_nn_part<<<dim3(D_D / 64, B_N / 64, 4), 256, 0, stream>>>(x1, W1, fpart, B_N, D_D, D_IN, D_IN / 4);
  k_rownorm_sum4_dual<<<B_N, 256, 0, stream>>>(fpart, f1, f1b);
  k_gemm_nn_part<<<dim3(D_D / 64, B_N / 64, 4), 256, 0, stream>>>(x2, W2, fpart, B_N, D_D, D_IN, D_IN / 4);
  k_rownorm_sum4<<<B_N, 256, 0, stream>>>(fpart, out_feat2);

  k_rownorm<<<K_C, 256, 0, stream>>>(c1, ctx1n);
  k_rownorm<<<K_C, 256, 0, stream>>>(c2, ctx2n);
  k_rownorm_bf16<<<L_Q, 256, 0, stream>>>(qn, qnnb);
  k_rownorm<<<KQ_, 256, 0, stream>>>(qk, qkn);
  k_rownorm_comb_bf16<<<KQ_, 256, 0, stream>>>(qkn, qnoise, qcombb);

  k_gemm_nt<<<dim3(K_C / 64, B_N / 64), 256, 0, stream>>>(f1, ctx1n, ybuf, B_N, K_C, D_D);
  k_gumbel<<<B_N, 256, 0, stream>>>(ybuf, u1a, u1b, out_assign, K_C);
  k_colsum<<<dim3(K_C / 256, 64), 256, 0, stream>>>(ybuf, norm1, B_N, K_C);
  k_gemm_tn<<<dim3(D_D / 64, K_C / 64, 16), 256, 0, stream>>>(ybuf, f1, aggt1, K_C, D_D, B_N / 16);
  k_rownorm_div_dual<<<K_C, 256, 0, stream>>>(aggt1, norm1, aggk1, aggk1b);

  k_gemm_nt<<<dim3(K_C / 64, B_N / 64), 256, 0, stream>>>(out_feat2, ctx2n, ybuf, B_N, K_C, D_D);
  k_gumbel<<<B_N, 256, 0, stream>>>(ybuf, u2a, nullptr, nullptr, K_C);
  k_colsum<<<dim3(K_C / 256, 64), 256, 0, stream>>>(ybuf, norm2, B_N, K_C);
  k_gemm_tn<<<dim3(D_D / 64, K_C / 64, 16), 256, 0, stream>>>(ybuf, out_feat2, aggt2, K_C, D_D, B_N / 16);
  k_rownorm_div<<<K_C, 256, 0, stream>>>(aggt2, norm2, out_aggk2);

  k_dotrows<<<B_N, 256, 0, stream>>>(f1, out_feat2, lpn);
  k_dotrows<<<K_C, 256, 0, stream>>>(aggk1, out_aggk2, lpk);

  k_lse2<<<dim3(8, B_N / 128), 512, 0, stream>>>((const short*)f1b, (const short*)qnnb, sen, L_Q / 8);
  k_lse2<<<dim3(8, K_C / 128), 512, 0, stream>>>((const short*)aggk1b, (const short*)qcombb, sek, KQ_ / 8);

  k_loss<<<1, 256, 0, stream>>>(lpn, sen, B_N, lpk, sek, K_C, out_loss);
}